// Round 1
// baseline (3608.312 us; speedup 1.0000x reference)
//
#include <hip/hip_runtime.h>
#include <hip/hip_bf16.h>
#include <math.h>

#define NBATCH 2
#define NSEQ   2048
#define NDIM   1024
#define NHEAD  16
#define NKVH   4
#define HDIM   64
#define KVD    256
#define NEXP   8
#define NINTER 512
#define NTOK   (NBATCH*NSEQ)
#define RMS_EPS 1.1920929e-07f
#define LN_10000 9.210340371976184f

__device__ __forceinline__ float wred64(float v) {
#pragma unroll
  for (int m = 32; m >= 1; m >>= 1) v += __shfl_xor(v, m);
  return v;
}

// ---------------- K1: xr = mix0*x + mix1*x0 ; n = rmsnorm(xr) ----------------
__global__ __launch_bounds__(256) void k_resid_rms(
    const float* __restrict__ x, const float* __restrict__ x0,
    const float* __restrict__ rmix, float* __restrict__ xr, float* __restrict__ nrm) {
  const int row = blockIdx.x;
  const int t = threadIdx.x;
  const int d = t * 4;
  const size_t base = (size_t)row * NDIM + d;
  float4 a  = *(const float4*)(x  + base);
  float4 b  = *(const float4*)(x0 + base);
  float4 m0 = *(const float4*)(rmix + d);
  float4 m1 = *(const float4*)(rmix + NDIM + d);
  float4 r;
  r.x = m0.x*a.x + m1.x*b.x;
  r.y = m0.y*a.y + m1.y*b.y;
  r.z = m0.z*a.z + m1.z*b.z;
  r.w = m0.w*a.w + m1.w*b.w;
  float ss = r.x*r.x + r.y*r.y + r.z*r.z + r.w*r.w;
  ss = wred64(ss);
  __shared__ float wsum[4];
  if ((t & 63) == 0) wsum[t >> 6] = ss;
  __syncthreads();
  float tot = wsum[0] + wsum[1] + wsum[2] + wsum[3];
  float rms = rsqrtf(tot * (1.0f/NDIM) + RMS_EPS);
  *(float4*)(xr + base) = r;
  float4 n4 = {r.x*rms, r.y*rms, r.z*rms, r.w*rms};
  *(float4*)(nrm + base) = n4;
}

// ---------------- K2: C[M,N] = A[M,K] . W[N,K]^T (row-dot-row) ----------------
__global__ __launch_bounds__(256) void k_gemm_nt(
    const float* __restrict__ A, const float* __restrict__ W,
    float* __restrict__ C, int M, int N, int K) {
  __shared__ float sA[16][68];
  __shared__ float sW[16][68];
  const int t = threadIdx.x;
  const int tx = t & 15, ty = t >> 4;
  const int row0 = blockIdx.y * 64, col0 = blockIdx.x * 64;
  const int lm = t >> 2;          // 0..63
  const int lk = (t & 3) * 4;     // 0,4,8,12
  float acc[4][4] = {};
  for (int k0 = 0; k0 < K; k0 += 16) {
    float4 a4 = *(const float4*)(A + (size_t)(row0 + lm)*K + k0 + lk);
    float4 w4 = *(const float4*)(W + (size_t)(col0 + lm)*K + k0 + lk);
    __syncthreads();
    sA[lk+0][lm] = a4.x; sA[lk+1][lm] = a4.y; sA[lk+2][lm] = a4.z; sA[lk+3][lm] = a4.w;
    sW[lk+0][lm] = w4.x; sW[lk+1][lm] = w4.y; sW[lk+2][lm] = w4.z; sW[lk+3][lm] = w4.w;
    __syncthreads();
#pragma unroll
    for (int kk = 0; kk < 16; ++kk) {
      float4 av = *(const float4*)&sA[kk][ty*4];
      float4 wv = *(const float4*)&sW[kk][tx*4];
      acc[0][0] += av.x*wv.x; acc[0][1] += av.x*wv.y; acc[0][2] += av.x*wv.z; acc[0][3] += av.x*wv.w;
      acc[1][0] += av.y*wv.x; acc[1][1] += av.y*wv.y; acc[1][2] += av.y*wv.z; acc[1][3] += av.y*wv.w;
      acc[2][0] += av.z*wv.x; acc[2][1] += av.z*wv.y; acc[2][2] += av.z*wv.z; acc[2][3] += av.z*wv.w;
      acc[3][0] += av.w*wv.x; acc[3][1] += av.w*wv.y; acc[3][2] += av.w*wv.z; acc[3][3] += av.w*wv.w;
    }
  }
#pragma unroll
  for (int i = 0; i < 4; ++i) {
    float4 c4 = {acc[i][0], acc[i][1], acc[i][2], acc[i][3]};
    *(float4*)(C + (size_t)(row0 + ty*4 + i)*N + col0 + tx*4) = c4;
  }
}

// --------- K3: per-head rmsnorm + rope + q_gain (in place on q,k) ---------
__global__ __launch_bounds__(256) void k_qk_norm_rope(
    float* __restrict__ q, float* __restrict__ k, const float* __restrict__ q_gain) {
  const int row = blockIdx.x;          // b*S+s
  const int t = threadIdx.x;
  const int w = t >> 6, lane = t & 63;
  const int s = row & (NSEQ - 1);
  const int fi = lane & 31;
  const float fr = (float)s * expf(-(float)fi * (LN_10000 / 32.0f));
  const float co = cosf(fr), si = sinf(fr);
#pragma unroll
  for (int h = w; h < NHEAD; h += 4) {
    float* p = q + (size_t)row*NDIM + h*HDIM + lane;
    float v = *p;
    float ssum = wred64(v*v);
    float rr = rsqrtf(ssum * (1.0f/HDIM) + RMS_EPS);
    float vn = v * rr;
    float partner = __shfl_xor(vn, 32);
    float out = (lane < 32) ? (vn*co + partner*si) : (vn*co - partner*si);
    *p = out * q_gain[h];
  }
  if (w < NKVH) {
    float* p = k + (size_t)row*KVD + w*HDIM + lane;
    float v = *p;
    float ssum = wred64(v*v);
    float rr = rsqrtf(ssum * (1.0f/HDIM) + RMS_EPS);
    float vn = v * rr;
    float partner = __shfl_xor(vn, 32);
    float out = (lane < 32) ? (vn*co + partner*si) : (vn*co - partner*si);
    *p = out;
  }
}

// ---------------- K4: causal flash attention, 64x64 tiles ----------------
__global__ __launch_bounds__(256) void k_attn(
    const float* __restrict__ q, const float* __restrict__ kg,
    const float* __restrict__ vg, float* __restrict__ y) {
  __shared__ float Qs[64][68];   // [kk][row], pre-scaled by 1/8
  __shared__ float Ks[64][68];   // [kk][col]
  __shared__ float Ps[64][68];   // [col][row]
  __shared__ float Vs[64][64];   // [col][dim]
  const int t = threadIdx.x;
  const int tx = t & 15, ty = t >> 4;
  const int bid = blockIdx.x;
  const int qt = bid & 31;
  const int h = (bid >> 5) & 15;
  const int b = bid >> 9;
  const int kh = h >> 2;
  const size_t qbase = ((size_t)(b*NSEQ) + qt*64) * NDIM + h*HDIM;
#pragma unroll
  for (int p = 0; p < 16; ++p) {
    int lin = p*256 + t;
    int r = lin >> 6, d = lin & 63;
    Qs[d][r] = q[qbase + (size_t)r*NDIM + d] * 0.125f;
  }
  float m_i[4], l_i[4], O[4][4];
#pragma unroll
  for (int i = 0; i < 4; ++i) {
    m_i[i] = -INFINITY; l_i[i] = 0.f;
#pragma unroll
    for (int j = 0; j < 4; ++j) O[i][j] = 0.f;
  }
  for (int kt = 0; kt <= qt; ++kt) {
    __syncthreads();   // prev iter consumed Ks/Vs/Ps; Qs ready (iter 0)
    const size_t kb = ((size_t)(b*NSEQ) + kt*64) * KVD + kh*HDIM;
#pragma unroll
    for (int p = 0; p < 16; ++p) {
      int lin = p*256 + t;
      int r = lin >> 6, d = lin & 63;
      Ks[d][r] = kg[kb + (size_t)r*KVD + d];
      Vs[r][d] = vg[kb + (size_t)r*KVD + d];
    }
    __syncthreads();
    float sc[4][4] = {};
#pragma unroll 8
    for (int c = 0; c < 64; ++c) {
      float4 qv = *(const float4*)&Qs[c][ty*4];
      float4 kv = *(const float4*)&Ks[c][tx*4];
      sc[0][0] += qv.x*kv.x; sc[0][1] += qv.x*kv.y; sc[0][2] += qv.x*kv.z; sc[0][3] += qv.x*kv.w;
      sc[1][0] += qv.y*kv.x; sc[1][1] += qv.y*kv.y; sc[1][2] += qv.y*kv.z; sc[1][3] += qv.y*kv.w;
      sc[2][0] += qv.z*kv.x; sc[2][1] += qv.z*kv.y; sc[2][2] += qv.z*kv.z; sc[2][3] += qv.z*kv.w;
      sc[3][0] += qv.w*kv.x; sc[3][1] += qv.w*kv.y; sc[3][2] += qv.w*kv.z; sc[3][3] += qv.w*kv.w;
    }
    if (kt == qt) {
#pragma unroll
      for (int i = 0; i < 4; ++i)
#pragma unroll
        for (int j = 0; j < 4; ++j)
          if (tx*4 + j > ty*4 + i) sc[i][j] = -INFINITY;
    }
    float fac[4];
#pragma unroll
    for (int i = 0; i < 4; ++i) {
      float rm = fmaxf(fmaxf(sc[i][0], sc[i][1]), fmaxf(sc[i][2], sc[i][3]));
#pragma unroll
      for (int m = 8; m >= 1; m >>= 1) rm = fmaxf(rm, __shfl_xor(rm, m));
      float mn = fmaxf(m_i[i], rm);
      fac[i] = __expf(m_i[i] - mn);
      float rs = 0.f;
#pragma unroll
      for (int j = 0; j < 4; ++j) { float pe = __expf(sc[i][j] - mn); sc[i][j] = pe; rs += pe; }
#pragma unroll
      for (int m = 8; m >= 1; m >>= 1) rs += __shfl_xor(rs, m);
      l_i[i] = l_i[i]*fac[i] + rs;
      m_i[i] = mn;
    }
#pragma unroll
    for (int j = 0; j < 4; ++j) {
      float4 pw = {sc[0][j], sc[1][j], sc[2][j], sc[3][j]};
      *(float4*)&Ps[tx*4+j][ty*4] = pw;
    }
#pragma unroll
    for (int i = 0; i < 4; ++i)
#pragma unroll
      for (int j = 0; j < 4; ++j) O[i][j] *= fac[i];
    __syncthreads();
#pragma unroll 8
    for (int c = 0; c < 64; ++c) {
      float4 pv = *(const float4*)&Ps[c][ty*4];
      float4 vv = *(const float4*)&Vs[c][tx*4];
      O[0][0] += pv.x*vv.x; O[0][1] += pv.x*vv.y; O[0][2] += pv.x*vv.z; O[0][3] += pv.x*vv.w;
      O[1][0] += pv.y*vv.x; O[1][1] += pv.y*vv.y; O[1][2] += pv.y*vv.z; O[1][3] += pv.y*vv.w;
      O[2][0] += pv.z*vv.x; O[2][1] += pv.z*vv.y; O[2][2] += pv.z*vv.z; O[2][3] += pv.z*vv.w;
      O[3][0] += pv.w*vv.x; O[3][1] += pv.w*vv.y; O[3][2] += pv.w*vv.z; O[3][3] += pv.w*vv.w;
    }
  }
#pragma unroll
  for (int i = 0; i < 4; ++i) {
    float inv = 1.0f / l_i[i];
    float4 o4 = {O[i][0]*inv, O[i][1]*inv, O[i][2]*inv, O[i][3]*inv};
    *(float4*)(y + qbase + (size_t)(ty*4+i)*NDIM + tx*4) = o4;
  }
}

// --------- K5: x1 = xr + as*attn ; v_next ; x2 -> out[0], v_next -> out[1] ---------
__global__ __launch_bounds__(256) void k_fuse_vel(
    const float* __restrict__ xr, const float* __restrict__ attn_out,
    const float* __restrict__ vel, const float* __restrict__ ascale,
    const float* __restrict__ mu, float* __restrict__ out) {
  const int gid = blockIdx.x * 256 + threadIdx.x;
  const size_t base = (size_t)gid * 4;
  const int d = (int)(base & (NDIM - 1));
  float4 a  = *(const float4*)(xr + base);
  float4 ao = *(const float4*)(attn_out + base);
  float4 vv = *(const float4*)(vel + base);
  float4 as = *(const float4*)(ascale + d);
  float4 mu4 = *(const float4*)(mu + d);
  float x1x = a.x + as.x*ao.x, x1y = a.y + as.y*ao.y, x1z = a.z + as.z*ao.z, x1w = a.w + as.w*ao.w;
  float mcx = fminf(fmaxf(mu4.x, 0.5f), 1.5f);
  float mcy = fminf(fmaxf(mu4.y, 0.5f), 1.5f);
  float mcz = fminf(fmaxf(mu4.z, 0.5f), 1.5f);
  float mcw = fminf(fmaxf(mu4.w, 0.5f), 1.5f);
  float vnx = fminf(fmaxf(0.95f*vv.x - 0.3f*(x1x - mcx), -3.f), 3.f);
  float vny = fminf(fmaxf(0.95f*vv.y - 0.3f*(x1y - mcy), -3.f), 3.f);
  float vnz = fminf(fmaxf(0.95f*vv.z - 0.3f*(x1z - mcz), -3.f), 3.f);
  float vnw = fminf(fmaxf(0.95f*vv.w - 0.3f*(x1w - mcw), -3.f), 3.f);
  float4 x2 = {x1x + 0.01f*vnx, x1y + 0.01f*vny, x1z + 0.01f*vnz, x1w + 0.01f*vnw};
  float4 vn = {vnx, vny, vnz, vnw};
  *(float4*)(out + base) = x2;
  *(float4*)(out + (size_t)NTOK*NDIM + base) = vn;
}

// --------- K6: MoE (token-routed), in place on out[0..NTOK*NDIM) ---------
__global__ __launch_bounds__(256) void k_moe(
    float* __restrict__ xout, const int* __restrict__ eids,
    const float* __restrict__ gate_up, const float* __restrict__ down,
    const float* __restrict__ mscale) {
  __shared__ float ms[NDIM];
  __shared__ float gus[2*NINTER];
  __shared__ float hs[NINTER];
  __shared__ float wsum[4];
  const int row = blockIdx.x;
  const int t = threadIdx.x;
  const int e = eids[row];
  const size_t base = (size_t)row * NDIM + t*4;
  float4 xv = *(const float4*)(xout + base);
  float ss = xv.x*xv.x + xv.y*xv.y + xv.z*xv.z + xv.w*xv.w;
  ss = wred64(ss);
  if ((t & 63) == 0) wsum[t >> 6] = ss;
  __syncthreads();
  float tot = wsum[0] + wsum[1] + wsum[2] + wsum[3];
  float rr = rsqrtf(tot * (1.0f/NDIM) + RMS_EPS);
  float4 m4 = {xv.x*rr, xv.y*rr, xv.z*rr, xv.w*rr};
  *(float4*)&ms[t*4] = m4;
  __syncthreads();
  // gate_up: gu[j] = sum_d ms[d] * GU[d][j], thread owns j = 4t..4t+3
  const float* GU = gate_up + (size_t)e * NDIM * (2*NINTER);
  float a0 = 0.f, a1 = 0.f, a2 = 0.f, a3 = 0.f;
  for (int dd = 0; dd < NDIM; ++dd) {
    float md = ms[dd];
    float4 w4 = *(const float4*)(GU + (size_t)dd*(2*NINTER) + t*4);
    a0 += md*w4.x; a1 += md*w4.y; a2 += md*w4.z; a3 += md*w4.w;
  }
  gus[t*4+0] = a0; gus[t*4+1] = a1; gus[t*4+2] = a2; gus[t*4+3] = a3;
  __syncthreads();
  if (t < 128) {
#pragma unroll
    for (int c = 0; c < 4; ++c) {
      int i = t*4 + c;
      float g = gus[i], u = gus[i + NINTER];
      hs[i] = (g / (1.0f + __expf(-g))) * u;
    }
  }
  __syncthreads();
  // down: o[j] = sum_i hs[i] * DW[i][j]
  const float* DW = down + (size_t)e * NINTER * NDIM;
  float b0 = 0.f, b1 = 0.f, b2 = 0.f, b3 = 0.f;
  for (int ii = 0; ii < NINTER; ++ii) {
    float hh = hs[ii];
    float4 w4 = *(const float4*)(DW + (size_t)ii*NDIM + t*4);
    b0 += hh*w4.x; b1 += hh*w4.y; b2 += hh*w4.z; b3 += hh*w4.w;
  }
  float4 sc4 = *(const float4*)(mscale + t*4);
  float4 res = {xv.x + sc4.x*b0, xv.y + sc4.y*b1, xv.z + sc4.z*b2, xv.w + sc4.w*b3};
  *(float4*)(xout + base) = res;
}

extern "C" void kernel_launch(void* const* d_in, const int* in_sizes, int n_in,
                              void* d_out, int out_size, void* d_ws, size_t ws_size,
                              hipStream_t stream) {
  const float* x      = (const float*)d_in[0];
  const float* x0     = (const float*)d_in[1];
  const float* vel    = (const float*)d_in[2];
  const float* rmix   = (const float*)d_in[3];
  const float* ascale = (const float*)d_in[4];
  const float* mscale = (const float*)d_in[5];
  const float* cq_w   = (const float*)d_in[6];
  const float* ck_w   = (const float*)d_in[7];
  const float* cv_w   = (const float*)d_in[8];
  const float* proj_w = (const float*)d_in[9];
  const float* q_gain = (const float*)d_in[10];
  const float* mu     = (const float*)d_in[11];
  const float* gate_up= (const float*)d_in[12];
  const float* down   = (const float*)d_in[13];
  const int*   eids   = (const int*)d_in[14];
  float* out = (float*)d_out;
  float* ws  = (float*)d_ws;

  float* xr   = ws;                       // 4M floats
  float* nbuf = xr   + (size_t)NTOK*NDIM; // 4M
  float* qbuf = nbuf + (size_t)NTOK*NDIM; // 4M
  float* kbuf = qbuf + (size_t)NTOK*NDIM; // 1M
  float* vbuf = kbuf + (size_t)NTOK*KVD;  // 1M
  float* ybuf = nbuf;   // reuse: n dead after QKV GEMMs
  float* aout = qbuf;   // reuse: q dead after attention

  k_resid_rms<<<NTOK, 256, 0, stream>>>(x, x0, rmix, xr, nbuf);
  k_gemm_nt<<<dim3(NDIM/64, NTOK/64), 256, 0, stream>>>(nbuf, cq_w, qbuf, NTOK, NDIM, NDIM);
  k_gemm_nt<<<dim3(KVD/64,  NTOK/64), 256, 0, stream>>>(nbuf, ck_w, kbuf, NTOK, KVD,  NDIM);
  k_gemm_nt<<<dim3(KVD/64,  NTOK/64), 256, 0, stream>>>(nbuf, cv_w, vbuf, NTOK, KVD,  NDIM);
  k_qk_norm_rope<<<NTOK, 256, 0, stream>>>(qbuf, kbuf, q_gain);
  k_attn<<<NBATCH*NHEAD*(NSEQ/64), 256, 0, stream>>>(qbuf, kbuf, vbuf, ybuf);
  k_gemm_nt<<<dim3(NDIM/64, NTOK/64), 256, 0, stream>>>(ybuf, proj_w, aout, NTOK, NDIM, NDIM);
  k_fuse_vel<<<(NTOK*NDIM)/(4*256), 256, 0, stream>>>(xr, aout, vel, ascale, mu, out);
  k_moe<<<NTOK, 256, 0, stream>>>(out, eids, gate_up, down, mscale);
}

// Round 3
// 1181.211 us; speedup vs baseline: 3.0548x; 3.0548x over previous
//
#include <hip/hip_runtime.h>
#include <hip/hip_bf16.h>
#include <math.h>

#define NBATCH 2
#define NSEQ   2048
#define NDIM   1024
#define NHEAD  16
#define NKVH   4
#define HDIM   64
#define KVD    256
#define NEXP   8
#define NINTER 512
#define NTOK   (NBATCH*NSEQ)
#define MAXTILE 72
#define RMS_EPS 1.1920929e-07f
#define LN_10000 9.210340371976184f

__device__ __forceinline__ float wred64(float v) {
#pragma unroll
  for (int m = 32; m >= 1; m >>= 1) v += __shfl_xor(v, m);
  return v;
}

// ---------------- K1: xr = mix0*x + mix1*x0 ; n = rmsnorm(xr) ----------------
__global__ __launch_bounds__(256) void k_resid_rms(
    const float* __restrict__ x, const float* __restrict__ x0,
    const float* __restrict__ rmix, float* __restrict__ xr, float* __restrict__ nrm) {
  const int row = blockIdx.x;
  const int t = threadIdx.x;
  const int d = t * 4;
  const size_t base = (size_t)row * NDIM + d;
  float4 a  = *(const float4*)(x  + base);
  float4 b  = *(const float4*)(x0 + base);
  float4 m0 = *(const float4*)(rmix + d);
  float4 m1 = *(const float4*)(rmix + NDIM + d);
  float4 r;
  r.x = m0.x*a.x + m1.x*b.x;
  r.y = m0.y*a.y + m1.y*b.y;
  r.z = m0.z*a.z + m1.z*b.z;
  r.w = m0.w*a.w + m1.w*b.w;
  float ss = r.x*r.x + r.y*r.y + r.z*r.z + r.w*r.w;
  ss = wred64(ss);
  __shared__ float wsum[4];
  if ((t & 63) == 0) wsum[t >> 6] = ss;
  __syncthreads();
  float tot = wsum[0] + wsum[1] + wsum[2] + wsum[3];
  float rms = rsqrtf(tot * (1.0f/NDIM) + RMS_EPS);
  *(float4*)(xr + base) = r;
  float4 n4 = {r.x*rms, r.y*rms, r.z*rms, r.w*rms};
  *(float4*)(nrm + base) = n4;
}

// ---------------- K2: C[M,N] = A[M,K] . W[N,K]^T (row-dot-row) ----------------
__global__ __launch_bounds__(256) void k_gemm_nt(
    const float* __restrict__ A, const float* __restrict__ W,
    float* __restrict__ C, int M, int N, int K) {
  __shared__ float sA[16][68];
  __shared__ float sW[16][68];
  const int t = threadIdx.x;
  const int tx = t & 15, ty = t >> 4;
  const int row0 = blockIdx.y * 64, col0 = blockIdx.x * 64;
  const int lm = t >> 2;          // 0..63
  const int lk = (t & 3) * 4;     // 0,4,8,12
  float acc[4][4] = {};
  for (int k0 = 0; k0 < K; k0 += 16) {
    float4 a4 = *(const float4*)(A + (size_t)(row0 + lm)*K + k0 + lk);
    float4 w4 = *(const float4*)(W + (size_t)(col0 + lm)*K + k0 + lk);
    __syncthreads();
    sA[lk+0][lm] = a4.x; sA[lk+1][lm] = a4.y; sA[lk+2][lm] = a4.z; sA[lk+3][lm] = a4.w;
    sW[lk+0][lm] = w4.x; sW[lk+1][lm] = w4.y; sW[lk+2][lm] = w4.z; sW[lk+3][lm] = w4.w;
    __syncthreads();
#pragma unroll
    for (int kk = 0; kk < 16; ++kk) {
      float4 av = *(const float4*)&sA[kk][ty*4];
      float4 wv = *(const float4*)&sW[kk][tx*4];
      acc[0][0] += av.x*wv.x; acc[0][1] += av.x*wv.y; acc[0][2] += av.x*wv.z; acc[0][3] += av.x*wv.w;
      acc[1][0] += av.y*wv.x; acc[1][1] += av.y*wv.y; acc[1][2] += av.y*wv.z; acc[1][3] += av.y*wv.w;
      acc[2][0] += av.z*wv.x; acc[2][1] += av.z*wv.y; acc[2][2] += av.z*wv.z; acc[2][3] += av.z*wv.w;
      acc[3][0] += av.w*wv.x; acc[3][1] += av.w*wv.y; acc[3][2] += av.w*wv.z; acc[3][3] += av.w*wv.w;
    }
  }
#pragma unroll
  for (int i = 0; i < 4; ++i) {
    float4 c4 = {acc[i][0], acc[i][1], acc[i][2], acc[i][3]};
    *(float4*)(C + (size_t)(row0 + ty*4 + i)*N + col0 + tx*4) = c4;
  }
}

// --------- K3: per-head rmsnorm + rope + q_gain (in place on q,k) ---------
__global__ __launch_bounds__(256) void k_qk_norm_rope(
    float* __restrict__ q, float* __restrict__ k, const float* __restrict__ q_gain) {
  const int row = blockIdx.x;          // b*S+s
  const int t = threadIdx.x;
  const int w = t >> 6, lane = t & 63;
  const int s = row & (NSEQ - 1);
  const int fi = lane & 31;
  const float fr = (float)s * expf(-(float)fi * (LN_10000 / 32.0f));
  const float co = cosf(fr), si = sinf(fr);
#pragma unroll
  for (int h = w; h < NHEAD; h += 4) {
    float* p = q + (size_t)row*NDIM + h*HDIM + lane;
    float v = *p;
    float ssum = wred64(v*v);
    float rr = rsqrtf(ssum * (1.0f/HDIM) + RMS_EPS);
    float vn = v * rr;
    float partner = __shfl_xor(vn, 32);
    float out = (lane < 32) ? (vn*co + partner*si) : (vn*co - partner*si);
    *p = out * q_gain[h];
  }
  if (w < NKVH) {
    float* p = k + (size_t)row*KVD + w*HDIM + lane;
    float v = *p;
    float ssum = wred64(v*v);
    float rr = rsqrtf(ssum * (1.0f/HDIM) + RMS_EPS);
    float vn = v * rr;
    float partner = __shfl_xor(vn, 32);
    float out = (lane < 32) ? (vn*co + partner*si) : (vn*co - partner*si);
    *p = out;
  }
}

// ---------------- K4: causal flash attention, 64x64 tiles ----------------
__global__ __launch_bounds__(256) void k_attn(
    const float* __restrict__ q, const float* __restrict__ kg,
    const float* __restrict__ vg, float* __restrict__ y) {
  __shared__ float Qs[64][68];   // [kk][row], pre-scaled by 1/8
  __shared__ float Ks[64][68];   // [kk][col]
  __shared__ float Ps[64][68];   // [col][row]
  __shared__ float Vs[64][64];   // [col][dim]
  const int t = threadIdx.x;
  const int tx = t & 15, ty = t >> 4;
  const int bid = blockIdx.x;
  const int qt = bid & 31;
  const int h = (bid >> 5) & 15;
  const int b = bid >> 9;
  const int kh = h >> 2;
  const size_t qbase = ((size_t)(b*NSEQ) + qt*64) * NDIM + h*HDIM;
#pragma unroll
  for (int p = 0; p < 16; ++p) {
    int lin = p*256 + t;
    int r = lin >> 6, d = lin & 63;
    Qs[d][r] = q[qbase + (size_t)r*NDIM + d] * 0.125f;
  }
  float m_i[4], l_i[4], O[4][4];
#pragma unroll
  for (int i = 0; i < 4; ++i) {
    m_i[i] = -INFINITY; l_i[i] = 0.f;
#pragma unroll
    for (int j = 0; j < 4; ++j) O[i][j] = 0.f;
  }
  for (int kt = 0; kt <= qt; ++kt) {
    __syncthreads();   // prev iter consumed Ks/Vs/Ps; Qs ready (iter 0)
    const size_t kb = ((size_t)(b*NSEQ) + kt*64) * KVD + kh*HDIM;
#pragma unroll
    for (int p = 0; p < 16; ++p) {
      int lin = p*256 + t;
      int r = lin >> 6, d = lin & 63;
      Ks[d][r] = kg[kb + (size_t)r*KVD + d];
      Vs[r][d] = vg[kb + (size_t)r*KVD + d];
    }
    __syncthreads();
    float sc[4][4] = {};
#pragma unroll 8
    for (int c = 0; c < 64; ++c) {
      float4 qv = *(const float4*)&Qs[c][ty*4];
      float4 kv = *(const float4*)&Ks[c][tx*4];
      sc[0][0] += qv.x*kv.x; sc[0][1] += qv.x*kv.y; sc[0][2] += qv.x*kv.z; sc[0][3] += qv.x*kv.w;
      sc[1][0] += qv.y*kv.x; sc[1][1] += qv.y*kv.y; sc[1][2] += qv.y*kv.z; sc[1][3] += qv.y*kv.w;
      sc[2][0] += qv.z*kv.x; sc[2][1] += qv.z*kv.y; sc[2][2] += qv.z*kv.z; sc[2][3] += qv.z*kv.w;
      sc[3][0] += qv.w*kv.x; sc[3][1] += qv.w*kv.y; sc[3][2] += qv.w*kv.z; sc[3][3] += qv.w*kv.w;
    }
    if (kt == qt) {
#pragma unroll
      for (int i = 0; i < 4; ++i)
#pragma unroll
        for (int j = 0; j < 4; ++j)
          if (tx*4 + j > ty*4 + i) sc[i][j] = -INFINITY;
    }
    float fac[4];
#pragma unroll
    for (int i = 0; i < 4; ++i) {
      float rm = fmaxf(fmaxf(sc[i][0], sc[i][1]), fmaxf(sc[i][2], sc[i][3]));
#pragma unroll
      for (int m = 8; m >= 1; m >>= 1) rm = fmaxf(rm, __shfl_xor(rm, m));
      float mn = fmaxf(m_i[i], rm);
      fac[i] = __expf(m_i[i] - mn);
      float rs = 0.f;
#pragma unroll
      for (int j = 0; j < 4; ++j) { float pe = __expf(sc[i][j] - mn); sc[i][j] = pe; rs += pe; }
#pragma unroll
      for (int m = 8; m >= 1; m >>= 1) rs += __shfl_xor(rs, m);
      l_i[i] = l_i[i]*fac[i] + rs;
      m_i[i] = mn;
    }
#pragma unroll
    for (int j = 0; j < 4; ++j) {
      float4 pw = {sc[0][j], sc[1][j], sc[2][j], sc[3][j]};
      *(float4*)&Ps[tx*4+j][ty*4] = pw;
    }
#pragma unroll
    for (int i = 0; i < 4; ++i)
#pragma unroll
      for (int j = 0; j < 4; ++j) O[i][j] *= fac[i];
    __syncthreads();
#pragma unroll 8
    for (int c = 0; c < 64; ++c) {
      float4 pv = *(const float4*)&Ps[c][ty*4];
      float4 vv = *(const float4*)&Vs[c][tx*4];
      O[0][0] += pv.x*vv.x; O[0][1] += pv.x*vv.y; O[0][2] += pv.x*vv.z; O[0][3] += pv.x*vv.w;
      O[1][0] += pv.y*vv.x; O[1][1] += pv.y*vv.y; O[1][2] += pv.y*vv.z; O[1][3] += pv.y*vv.w;
      O[2][0] += pv.z*vv.x; O[2][1] += pv.z*vv.y; O[2][2] += pv.z*vv.z; O[2][3] += pv.z*vv.w;
      O[3][0] += pv.w*vv.x; O[3][1] += pv.w*vv.y; O[3][2] += pv.w*vv.z; O[3][3] += pv.w*vv.w;
    }
  }
#pragma unroll
  for (int i = 0; i < 4; ++i) {
    float inv = 1.0f / l_i[i];
    float4 o4 = {O[i][0]*inv, O[i][1]*inv, O[i][2]*inv, O[i][3]*inv};
    *(float4*)(y + qbase + (size_t)(ty*4+i)*NDIM + tx*4) = o4;
  }
}

// --------- K5: x2/v_next -> out ; mbuf = rmsnorm(x2) ---------
__global__ __launch_bounds__(256) void k_fuse_vel(
    const float* __restrict__ xr, const float* __restrict__ attn_out,
    const float* __restrict__ vel, const float* __restrict__ ascale,
    const float* __restrict__ mu, float* __restrict__ out, float* __restrict__ mbuf) {
  const int row = blockIdx.x;
  const int t = threadIdx.x;
  const int d = t * 4;
  const size_t base = (size_t)row * NDIM + d;
  float4 a  = *(const float4*)(xr + base);
  float4 ao = *(const float4*)(attn_out + base);
  float4 vv = *(const float4*)(vel + base);
  float4 as = *(const float4*)(ascale + d);
  float4 mu4 = *(const float4*)(mu + d);
  float x1x = a.x + as.x*ao.x, x1y = a.y + as.y*ao.y, x1z = a.z + as.z*ao.z, x1w = a.w + as.w*ao.w;
  float mcx = fminf(fmaxf(mu4.x, 0.5f), 1.5f);
  float mcy = fminf(fmaxf(mu4.y, 0.5f), 1.5f);
  float mcz = fminf(fmaxf(mu4.z, 0.5f), 1.5f);
  float mcw = fminf(fmaxf(mu4.w, 0.5f), 1.5f);
  float vnx = fminf(fmaxf(0.95f*vv.x - 0.3f*(x1x - mcx), -3.f), 3.f);
  float vny = fminf(fmaxf(0.95f*vv.y - 0.3f*(x1y - mcy), -3.f), 3.f);
  float vnz = fminf(fmaxf(0.95f*vv.z - 0.3f*(x1z - mcz), -3.f), 3.f);
  float vnw = fminf(fmaxf(0.95f*vv.w - 0.3f*(x1w - mcw), -3.f), 3.f);
  float4 x2 = {x1x + 0.01f*vnx, x1y + 0.01f*vny, x1z + 0.01f*vnz, x1w + 0.01f*vnw};
  float4 vn = {vnx, vny, vnz, vnw};
  *(float4*)(out + base) = x2;
  *(float4*)(out + (size_t)NTOK*NDIM + base) = vn;
  float ss = x2.x*x2.x + x2.y*x2.y + x2.z*x2.z + x2.w*x2.w;
  ss = wred64(ss);
  __shared__ float wsum[4];
  if ((t & 63) == 0) wsum[t >> 6] = ss;
  __syncthreads();
  float tot = wsum[0] + wsum[1] + wsum[2] + wsum[3];
  float rms = rsqrtf(tot * (1.0f/NDIM) + RMS_EPS);
  float4 m4 = {x2.x*rms, x2.y*rms, x2.z*rms, x2.w*rms};
  *(float4*)(mbuf + base) = m4;
}

// --------- K6a: token routing (histogram + prefix + scatter + tile table) ---------
__global__ __launch_bounds__(256) void k_route(
    const int* __restrict__ eids, int* __restrict__ rowmap,
    int* __restrict__ tiletab, int* __restrict__ meta) {
  __shared__ int cnt[NEXP];
  __shared__ int ctr[NEXP];
  const int t = threadIdx.x;
  if (t < NEXP) cnt[t] = 0;
  __syncthreads();
  for (int i = t; i < NTOK; i += 256) atomicAdd(&cnt[eids[i]], 1);
  __syncthreads();
  if (t == 0) {
    int off = 0, tile = 0;
    for (int e = 0; e < NEXP; ++e) {
      ctr[e] = off;
      int nt_e = (cnt[e] + 63) >> 6;
      for (int j = 0; j < nt_e; ++j) { tiletab[2*tile] = e; tiletab[2*tile+1] = off + j*64; ++tile; }
      off += cnt[e];
      meta[1 + e] = off;   // end offset of expert e
    }
    meta[0] = tile;
    for (int j = tile; j < MAXTILE; ++j) { tiletab[2*j] = -1; tiletab[2*j+1] = 0; }
  }
  __syncthreads();
  for (int i = t; i < NTOK; i += 256) {
    int e = eids[i];
    int slot = atomicAdd(&ctr[e], 1);
    rowmap[slot] = i;
  }
}

// --------- K6b: grouped GEMM1: h = silu(m.Wg) * (m.Wu), compact rows ---------
__global__ __launch_bounds__(256) void k_moe_gemm1(
    const float* __restrict__ mbuf, const float* __restrict__ gate_up,
    const int* __restrict__ rowmap, const int* __restrict__ tiletab,
    const int* __restrict__ meta, float* __restrict__ hbuf) {
  const int e = tiletab[2*blockIdx.y];
  if (e < 0) return;
  const int slot0 = tiletab[2*blockIdx.y + 1];
  const int end = meta[1 + e];
  __shared__ float sA[16][68];
  __shared__ float sBg[16][68];
  __shared__ float sBu[16][68];
  const int t = threadIdx.x;
  const int tx = t & 15, ty = t >> 4;
  const int col0 = blockIdx.x * 64;
  const int lm = t >> 2, lk = (t & 3) * 4;
  const int kr = t >> 4, cc = (t & 15) * 4;
  const int slotA = slot0 + lm;
  const int tokA = (slotA < end) ? rowmap[slotA] : 0;
  const float* B = gate_up + (size_t)e * NDIM * (2*NINTER);
  float ag[4][4] = {};
  float au[4][4] = {};
  for (int k0 = 0; k0 < NDIM; k0 += 16) {
    float4 a4 = *(const float4*)(mbuf + (size_t)tokA*NDIM + k0 + lk);
    float4 bg = *(const float4*)(B + (size_t)(k0+kr)*(2*NINTER) + col0 + cc);
    float4 bu = *(const float4*)(B + (size_t)(k0+kr)*(2*NINTER) + NINTER + col0 + cc);
    __syncthreads();
    sA[lk+0][lm] = a4.x; sA[lk+1][lm] = a4.y; sA[lk+2][lm] = a4.z; sA[lk+3][lm] = a4.w;
    *(float4*)&sBg[kr][cc] = bg;
    *(float4*)&sBu[kr][cc] = bu;
    __syncthreads();
#pragma unroll
    for (int kk = 0; kk < 16; ++kk) {
      float4 av = *(const float4*)&sA[kk][ty*4];
      float4 bgv = *(const float4*)&sBg[kk][tx*4];
      float4 buv = *(const float4*)&sBu[kk][tx*4];
      ag[0][0] += av.x*bgv.x; ag[0][1] += av.x*bgv.y; ag[0][2] += av.x*bgv.z; ag[0][3] += av.x*bgv.w;
      ag[1][0] += av.y*bgv.x; ag[1][1] += av.y*bgv.y; ag[1][2] += av.y*bgv.z; ag[1][3] += av.y*bgv.w;
      ag[2][0] += av.z*bgv.x; ag[2][1] += av.z*bgv.y; ag[2][2] += av.z*bgv.z; ag[2][3] += av.z*bgv.w;
      ag[3][0] += av.w*bgv.x; ag[3][1] += av.w*bgv.y; ag[3][2] += av.w*bgv.z; ag[3][3] += av.w*bgv.w;
      au[0][0] += av.x*buv.x; au[0][1] += av.x*buv.y; au[0][2] += av.x*buv.z; au[0][3] += av.x*buv.w;
      au[1][0] += av.y*buv.x; au[1][1] += av.y*buv.y; au[1][2] += av.y*buv.z; au[1][3] += av.y*buv.w;
      au[2][0] += av.z*buv.x; au[2][1] += av.z*buv.y; au[2][2] += av.z*buv.z; au[2][3] += av.z*buv.w;
      au[3][0] += av.w*buv.x; au[3][1] += av.w*buv.y; au[3][2] += av.w*buv.z; au[3][3] += av.w*buv.w;
    }
  }
#pragma unroll
  for (int i = 0; i < 4; ++i) {
    // guard: expert tail tiles overlap the next expert's slot range in hbuf;
    // only the owning expert (slot < end) may write a row.
    if (slot0 + ty*4 + i < end) {
#pragma unroll
      for (int j = 0; j < 4; ++j) {
        float g = ag[i][j], u = au[i][j];
        float h = (g / (1.0f + __expf(-g))) * u;
        hbuf[(size_t)(slot0 + ty*4 + i)*NINTER + col0 + tx*4 + j] = h;
      }
    }
  }
}

// --------- K6c: grouped GEMM2: out[tok] += mscale * (h . Wd), scatter rows ---------
__global__ __launch_bounds__(256) void k_moe_gemm2(
    const float* __restrict__ hbuf, const float* __restrict__ down,
    const int* __restrict__ rowmap, const int* __restrict__ tiletab,
    const int* __restrict__ meta, const float* __restrict__ mscale,
    float* __restrict__ out) {
  const int e = tiletab[2*blockIdx.y];
  if (e < 0) return;
  const int slot0 = tiletab[2*blockIdx.y + 1];
  const int end = meta[1 + e];
  __shared__ float sA[16][68];
  __shared__ float sB[16][68];
  const int t = threadIdx.x;
  const int tx = t & 15, ty = t >> 4;
  const int col0 = blockIdx.x * 64;
  const int lm = t >> 2, lk = (t & 3) * 4;
  const int kr = t >> 4, cc = (t & 15) * 4;
  const float* B = down + (size_t)e * NINTER * NDIM;
  float acc[4][4] = {};
  for (int k0 = 0; k0 < NINTER; k0 += 16) {
    float4 a4 = *(const float4*)(hbuf + (size_t)(slot0 + lm)*NINTER + k0 + lk);
    float4 b4 = *(const float4*)(B + (size_t)(k0+kr)*NDIM + col0 + cc);
    __syncthreads();
    sA[lk+0][lm] = a4.x; sA[lk+1][lm] = a4.y; sA[lk+2][lm] = a4.z; sA[lk+3][lm] = a4.w;
    *(float4*)&sB[kr][cc] = b4;
    __syncthreads();
#pragma unroll
    for (int kk = 0; kk < 16; ++kk) {
      float4 av = *(const float4*)&sA[kk][ty*4];
      float4 bv = *(const float4*)&sB[kk][tx*4];
      acc[0][0] += av.x*bv.x; acc[0][1] += av.x*bv.y; acc[0][2] += av.x*bv.z; acc[0][3] += av.x*bv.w;
      acc[1][0] += av.y*bv.x; acc[1][1] += av.y*bv.y; acc[1][2] += av.y*bv.z; acc[1][3] += av.y*bv.w;
      acc[2][0] += av.z*bv.x; acc[2][1] += av.z*bv.y; acc[2][2] += av.z*bv.z; acc[2][3] += av.z*bv.w;
      acc[3][0] += av.w*bv.x; acc[3][1] += av.w*bv.y; acc[3][2] += av.w*bv.z; acc[3][3] += av.w*bv.w;
    }
  }
#pragma unroll
  for (int i = 0; i < 4; ++i) {
    int slot = slot0 + ty*4 + i;
    if (slot < end) {
      int tok = rowmap[slot];
      float* op = out + (size_t)tok*NDIM + col0 + tx*4;
      const float* sp = mscale + col0 + tx*4;
#pragma unroll
      for (int j = 0; j < 4; ++j) op[j] += sp[j] * acc[i][j];
    }
  }
}

extern "C" void kernel_launch(void* const* d_in, const int* in_sizes, int n_in,
                              void* d_out, int out_size, void* d_ws, size_t ws_size,
                              hipStream_t stream) {
  const float* x      = (const float*)d_in[0];
  const float* x0     = (const float*)d_in[1];
  const float* vel    = (const float*)d_in[2];
  const float* rmix   = (const float*)d_in[3];
  const float* ascale = (const float*)d_in[4];
  const float* mscale = (const float*)d_in[5];
  const float* cq_w   = (const float*)d_in[6];
  const float* ck_w   = (const float*)d_in[7];
  const float* cv_w   = (const float*)d_in[8];
  const float* proj_w = (const float*)d_in[9];
  const float* q_gain = (const float*)d_in[10];
  const float* mu     = (const float*)d_in[11];
  const float* gate_up= (const float*)d_in[12];
  const float* down   = (const float*)d_in[13];
  const int*   eids   = (const int*)d_in[14];
  float* out = (float*)d_out;
  float* ws  = (float*)d_ws;

  float* xr   = ws;                       // 4M floats
  float* nbuf = xr   + (size_t)NTOK*NDIM; // 4M
  float* qbuf = nbuf + (size_t)NTOK*NDIM; // 4M
  float* kbuf = qbuf + (size_t)NTOK*NDIM; // 1M
  float* vbuf = kbuf + (size_t)NTOK*KVD;  // 1M
  float* ybuf = nbuf;   // reuse: n dead after QKV GEMMs
  float* aout = qbuf;   // reuse: q dead after attention
  float* mbuf = nbuf;   // reuse: y dead after proj GEMM
  float* hbuf = xr;     // reuse: xr dead after k_fuse_vel (needs ~2.1M floats)
  int* rowmap = (int*)kbuf;              // reuse: k dead after attention (4096 ints)
  int* tiletab = rowmap + NTOK;          // 144 ints
  int* meta = tiletab + 2*MAXTILE;       // 9 ints

  k_resid_rms<<<NTOK, 256, 0, stream>>>(x, x0, rmix, xr, nbuf);
  k_gemm_nt<<<dim3(NDIM/64, NTOK/64), 256, 0, stream>>>(nbuf, cq_w, qbuf, NTOK, NDIM, NDIM);
  k_gemm_nt<<<dim3(KVD/64,  NTOK/64), 256, 0, stream>>>(nbuf, ck_w, kbuf, NTOK, KVD,  NDIM);
  k_gemm_nt<<<dim3(KVD/64,  NTOK/64), 256, 0, stream>>>(nbuf, cv_w, vbuf, NTOK, KVD,  NDIM);
  k_qk_norm_rope<<<NTOK, 256, 0, stream>>>(qbuf, kbuf, q_gain);
  k_attn<<<NBATCH*NHEAD*(NSEQ/64), 256, 0, stream>>>(qbuf, kbuf, vbuf, ybuf);
  k_gemm_nt<<<dim3(NDIM/64, NTOK/64), 256, 0, stream>>>(ybuf, proj_w, aout, NTOK, NDIM, NDIM);
  k_fuse_vel<<<NTOK, 256, 0, stream>>>(xr, aout, vel, ascale, mu, out, mbuf);
  k_route<<<1, 256, 0, stream>>>(eids, rowmap, tiletab, meta);
  k_moe_gemm1<<<dim3(NINTER/64, MAXTILE), 256, 0, stream>>>(mbuf, gate_up, rowmap, tiletab, meta, hbuf);
  k_moe_gemm2<<<dim3(NDIM/64, MAXTILE), 256, 0, stream>>>(hbuf, down, rowmap, tiletab, meta, mscale, out);
}

// Round 4
// 801.668 us; speedup vs baseline: 4.5010x; 1.4734x over previous
//
#include <hip/hip_runtime.h>
#include <hip/hip_bf16.h>
#include <math.h>
#include <type_traits>

#define NBATCH 2
#define NSEQ   2048
#define NDIM   1024
#define NHEAD  16
#define NKVH   4
#define HDIM   64
#define KVD    256
#define NEXP   8
#define NINTER 512
#define NTOK   (NBATCH*NSEQ)
#define MAXTILE 72
#define RMS_EPS 1.1920929e-07f
#define LN_10000 9.210340371976184f

typedef __attribute__((ext_vector_type(8))) short bf16x8;
typedef __attribute__((ext_vector_type(4))) short short4v;
typedef __attribute__((ext_vector_type(4))) float f32x4;

__device__ __forceinline__ short f2b(float f) {
  unsigned u = __builtin_bit_cast(unsigned, f);
  unsigned r = (u + 0x7fffu + ((u >> 16) & 1u)) >> 16;  // RNE
  return (short)r;
}
__device__ __forceinline__ float b2f(short s) {
  unsigned u = ((unsigned)(unsigned short)s) << 16;
  return __builtin_bit_cast(float, u);
}

__device__ __forceinline__ float wred64(float v) {
#pragma unroll
  for (int m = 32; m >= 1; m >>= 1) v += __shfl_xor(v, m);
  return v;
}

// ---------------- K1: xr = mix0*x + mix1*x0 ; n = rmsnorm(xr) ----------------
__global__ __launch_bounds__(256) void k_resid_rms(
    const float* __restrict__ x, const float* __restrict__ x0,
    const float* __restrict__ rmix, float* __restrict__ xr, float* __restrict__ nrm) {
  const int row = blockIdx.x;
  const int t = threadIdx.x;
  const int d = t * 4;
  const size_t base = (size_t)row * NDIM + d;
  float4 a  = *(const float4*)(x  + base);
  float4 b  = *(const float4*)(x0 + base);
  float4 m0 = *(const float4*)(rmix + d);
  float4 m1 = *(const float4*)(rmix + NDIM + d);
  float4 r;
  r.x = m0.x*a.x + m1.x*b.x;
  r.y = m0.y*a.y + m1.y*b.y;
  r.z = m0.z*a.z + m1.z*b.z;
  r.w = m0.w*a.w + m1.w*b.w;
  float ss = r.x*r.x + r.y*r.y + r.z*r.z + r.w*r.w;
  ss = wred64(ss);
  __shared__ float wsum[4];
  if ((t & 63) == 0) wsum[t >> 6] = ss;
  __syncthreads();
  float tot = wsum[0] + wsum[1] + wsum[2] + wsum[3];
  float rms = rsqrtf(tot * (1.0f/NDIM) + RMS_EPS);
  *(float4*)(xr + base) = r;
  float4 n4 = {r.x*rms, r.y*rms, r.z*rms, r.w*rms};
  *(float4*)(nrm + base) = n4;
}

// ------- K2: C[M,N] = A[M,K] . W[N,K]^T ; OutT = float or short(bf16) -------
template <typename OutT>
__global__ __launch_bounds__(256) void k_gemm_nt(
    const float* __restrict__ A, const float* __restrict__ W,
    OutT* __restrict__ C, int M, int N, int K) {
  __shared__ float sA[16][68];
  __shared__ float sW[16][68];
  const int t = threadIdx.x;
  const int tx = t & 15, ty = t >> 4;
  const int row0 = blockIdx.y * 64, col0 = blockIdx.x * 64;
  const int lm = t >> 2;          // 0..63
  const int lk = (t & 3) * 4;     // 0,4,8,12
  float acc[4][4] = {};
  for (int k0 = 0; k0 < K; k0 += 16) {
    float4 a4 = *(const float4*)(A + (size_t)(row0 + lm)*K + k0 + lk);
    float4 w4 = *(const float4*)(W + (size_t)(col0 + lm)*K + k0 + lk);
    __syncthreads();
    sA[lk+0][lm] = a4.x; sA[lk+1][lm] = a4.y; sA[lk+2][lm] = a4.z; sA[lk+3][lm] = a4.w;
    sW[lk+0][lm] = w4.x; sW[lk+1][lm] = w4.y; sW[lk+2][lm] = w4.z; sW[lk+3][lm] = w4.w;
    __syncthreads();
#pragma unroll
    for (int kk = 0; kk < 16; ++kk) {
      float4 av = *(const float4*)&sA[kk][ty*4];
      float4 wv = *(const float4*)&sW[kk][tx*4];
      acc[0][0] += av.x*wv.x; acc[0][1] += av.x*wv.y; acc[0][2] += av.x*wv.z; acc[0][3] += av.x*wv.w;
      acc[1][0] += av.y*wv.x; acc[1][1] += av.y*wv.y; acc[1][2] += av.y*wv.z; acc[1][3] += av.y*wv.w;
      acc[2][0] += av.z*wv.x; acc[2][1] += av.z*wv.y; acc[2][2] += av.z*wv.z; acc[2][3] += av.z*wv.w;
      acc[3][0] += av.w*wv.x; acc[3][1] += av.w*wv.y; acc[3][2] += av.w*wv.z; acc[3][3] += av.w*wv.w;
    }
  }
#pragma unroll
  for (int i = 0; i < 4; ++i) {
    if constexpr (std::is_same<OutT, float>::value) {
      float4 c4 = {acc[i][0], acc[i][1], acc[i][2], acc[i][3]};
      *(float4*)(C + (size_t)(row0 + ty*4 + i)*N + col0 + tx*4) = c4;
    } else {
      short4v c4 = {f2b(acc[i][0]), f2b(acc[i][1]), f2b(acc[i][2]), f2b(acc[i][3])};
      *(short4v*)(C + (size_t)(row0 + ty*4 + i)*N + col0 + tx*4) = c4;
    }
  }
}

// --------- K3: per-head rmsnorm + rope (+0.125*q_gain folded), bf16 in-place ---------
__global__ __launch_bounds__(256) void k_qk_norm_rope(
    short* __restrict__ q, short* __restrict__ k, const float* __restrict__ q_gain) {
  const int row = blockIdx.x;          // b*S+s
  const int t = threadIdx.x;
  const int w = t >> 6, lane = t & 63;
  const int s = row & (NSEQ - 1);
  const int fi = lane & 31;
  const float fr = (float)s * expf(-(float)fi * (LN_10000 / 32.0f));
  const float co = cosf(fr), si = sinf(fr);
#pragma unroll
  for (int h = w; h < NHEAD; h += 4) {
    short* p = q + (size_t)row*NDIM + h*HDIM + lane;
    float v = b2f(*p);
    float ssum = wred64(v*v);
    float rr = rsqrtf(ssum * (1.0f/HDIM) + RMS_EPS);
    float vn = v * rr;
    float partner = __shfl_xor(vn, 32);
    float o = (lane < 32) ? (vn*co + partner*si) : (vn*co - partner*si);
    *p = f2b(o * q_gain[h] * 0.125f);
  }
  if (w < NKVH) {
    short* p = k + (size_t)row*KVD + w*HDIM + lane;
    float v = b2f(*p);
    float ssum = wred64(v*v);
    float rr = rsqrtf(ssum * (1.0f/HDIM) + RMS_EPS);
    float vn = v * rr;
    float partner = __shfl_xor(vn, 32);
    float o = (lane < 32) ? (vn*co + partner*si) : (vn*co - partner*si);
    *p = f2b(o);
  }
}

// --------- K3b: V transpose to [b][kh][dim][seq] bf16 ---------
__global__ __launch_bounds__(256) void k_transpose_v(
    const short* __restrict__ vb, short* __restrict__ vbT) {
  __shared__ short T[64*72];
  const int blk = blockIdx.x;
  const int st = blk & 31, kh = (blk >> 5) & 3, b = blk >> 7;
  const int t = threadIdx.x;
#pragma unroll
  for (int i = 0; i < 2; ++i) {
    int c = t + i*256;
    int s = c >> 3, d0 = (c & 7) * 8;
    bf16x8 v = *(const bf16x8*)(vb + (size_t)(b*NSEQ + st*64 + s)*KVD + kh*HDIM + d0);
#pragma unroll
    for (int j = 0; j < 8; ++j) T[(d0 + j)*72 + s] = v[j];
  }
  __syncthreads();
#pragma unroll
  for (int i = 0; i < 2; ++i) {
    int c = t + i*256;
    int d = c >> 3, s0 = (c & 7) * 8;
    *(bf16x8*)(vbT + (size_t)((b*NKVH + kh)*HDIM + d)*NSEQ + st*64 + s0) = *(bf16x8*)&T[d*72 + s0];
  }
}

// ---------------- K4: causal flash attention, MFMA bf16 16x16x32 ----------------
// Layouts (guide-verified): A-frag lane&15=row, k=(lane>>4)*8+j ;
// B-frag lane&15=col, k=(lane>>4)*8+j ; C/D col=lane&15, row=(lane>>4)*4+reg.
__global__ __launch_bounds__(256) void k_attn_mfma(
    const short* __restrict__ qb, const short* __restrict__ kb,
    const short* __restrict__ vbT, float* __restrict__ y) {
  __shared__ short Ks[64*72];   // [key][dim]
  __shared__ short Vt[64*72];   // [dim][key]
  __shared__ short Ps[64*72];   // [qrow][key], per-wave-private rows
  const int t = threadIdx.x;
  const int l = t & 63, w = t >> 6;
  const int lrow = l & 15, lk8 = (l >> 4) * 8;
  const int bid = blockIdx.x;
  const int qt = bid & 31, h = (bid >> 5) & 15, b = bid >> 9;
  const int kh = h >> 2;
  const int qrow_g = b*NSEQ + qt*64 + w*16 + lrow;
  bf16x8 qf0 = *(const bf16x8*)(qb + (size_t)qrow_g*NDIM + h*HDIM + lk8);
  bf16x8 qf1 = *(const bf16x8*)(qb + (size_t)qrow_g*NDIM + h*HDIM + 32 + lk8);
  float m_i[4], l_i[4];
  f32x4 O[4];
#pragma unroll
  for (int r = 0; r < 4; ++r) { m_i[r] = -INFINITY; l_i[r] = 0.f; }
#pragma unroll
  for (int db = 0; db < 4; ++db)
#pragma unroll
    for (int r = 0; r < 4; ++r) O[db][r] = 0.f;

  for (int kt = 0; kt <= qt; ++kt) {
    __syncthreads();   // all waves done reading Ks/Vt from previous iter
#pragma unroll
    for (int i = 0; i < 2; ++i) {
      int c = t + i*256;
      int r0 = c >> 3, d0 = (c & 7) * 8;
      *(bf16x8*)&Ks[r0*72 + d0] =
          *(const bf16x8*)(kb + (size_t)(b*NSEQ + kt*64 + r0)*KVD + kh*HDIM + d0);
      *(bf16x8*)&Vt[r0*72 + d0] =
          *(const bf16x8*)(vbT + (size_t)((b*NKVH + kh)*HDIM + r0)*NSEQ + kt*64 + d0);
    }
    __syncthreads();
    f32x4 sc[4];
#pragma unroll
    for (int nb = 0; nb < 4; ++nb)
#pragma unroll
      for (int r = 0; r < 4; ++r) sc[nb][r] = 0.f;
#pragma unroll
    for (int nb = 0; nb < 4; ++nb) {
      bf16x8 kf0 = *(const bf16x8*)&Ks[(nb*16 + lrow)*72 + lk8];
      bf16x8 kf1 = *(const bf16x8*)&Ks[(nb*16 + lrow)*72 + 32 + lk8];
      sc[nb] = __builtin_amdgcn_mfma_f32_16x16x32_bf16(qf0, kf0, sc[nb], 0, 0, 0);
      sc[nb] = __builtin_amdgcn_mfma_f32_16x16x32_bf16(qf1, kf1, sc[nb], 0, 0, 0);
    }
    if (kt == qt) {
#pragma unroll
      for (int nb = 0; nb < 4; ++nb)
#pragma unroll
        for (int r = 0; r < 4; ++r)
          if (nb*16 + lrow > w*16 + (l >> 4)*4 + r) sc[nb][r] = -INFINITY;
    }
#pragma unroll
    for (int r = 0; r < 4; ++r) {
      float rm = fmaxf(fmaxf(sc[0][r], sc[1][r]), fmaxf(sc[2][r], sc[3][r]));
      rm = fmaxf(rm, __shfl_xor(rm, 1));
      rm = fmaxf(rm, __shfl_xor(rm, 2));
      rm = fmaxf(rm, __shfl_xor(rm, 4));
      rm = fmaxf(rm, __shfl_xor(rm, 8));
      float mn = fmaxf(m_i[r], rm);
      float fac = __expf(m_i[r] - mn);
      float rs = 0.f;
#pragma unroll
      for (int nb = 0; nb < 4; ++nb) {
        float p = __expf(sc[nb][r] - mn);
        sc[nb][r] = p;
        rs += p;
      }
      rs += __shfl_xor(rs, 1);
      rs += __shfl_xor(rs, 2);
      rs += __shfl_xor(rs, 4);
      rs += __shfl_xor(rs, 8);
      l_i[r] = l_i[r]*fac + rs;
      m_i[r] = mn;
#pragma unroll
      for (int db = 0; db < 4; ++db) O[db][r] *= fac;
    }
    // P -> LDS (own-wave rows only; wave-ordered DS ops, no barrier needed)
#pragma unroll
    for (int nb = 0; nb < 4; ++nb)
#pragma unroll
      for (int r = 0; r < 4; ++r)
        Ps[(w*16 + (l >> 4)*4 + r)*72 + nb*16 + lrow] = f2b(sc[nb][r]);
    bf16x8 pf0 = *(const bf16x8*)&Ps[(w*16 + lrow)*72 + lk8];
    bf16x8 pf1 = *(const bf16x8*)&Ps[(w*16 + lrow)*72 + 32 + lk8];
#pragma unroll
    for (int db = 0; db < 4; ++db) {
      bf16x8 vf0 = *(const bf16x8*)&Vt[(db*16 + lrow)*72 + lk8];
      bf16x8 vf1 = *(const bf16x8*)&Vt[(db*16 + lrow)*72 + 32 + lk8];
      O[db] = __builtin_amdgcn_mfma_f32_16x16x32_bf16(pf0, vf0, O[db], 0, 0, 0);
      O[db] = __builtin_amdgcn_mfma_f32_16x16x32_bf16(pf1, vf1, O[db], 0, 0, 0);
    }
  }
#pragma unroll
  for (int r = 0; r < 4; ++r) {
    float inv = 1.0f / l_i[r];
    int rowo = b*NSEQ + qt*64 + w*16 + (l >> 4)*4 + r;
#pragma unroll
    for (int db = 0; db < 4; ++db)
      y[(size_t)rowo*NDIM + h*HDIM + db*16 + lrow] = O[db][r] * inv;
  }
}

// --------- K5: x2/v_next -> out ; mbuf = rmsnorm(x2) ---------
__global__ __launch_bounds__(256) void k_fuse_vel(
    const float* __restrict__ xr, const float* __restrict__ attn_out,
    const float* __restrict__ vel, const float* __restrict__ ascale,
    const float* __restrict__ mu, float* __restrict__ out, float* __restrict__ mbuf) {
  const int row = blockIdx.x;
  const int t = threadIdx.x;
  const int d = t * 4;
  const size_t base = (size_t)row * NDIM + d;
  float4 a  = *(const float4*)(xr + base);
  float4 ao = *(const float4*)(attn_out + base);
  float4 vv = *(const float4*)(vel + base);
  float4 as = *(const float4*)(ascale + d);
  float4 mu4 = *(const float4*)(mu + d);
  float x1x = a.x + as.x*ao.x, x1y = a.y + as.y*ao.y, x1z = a.z + as.z*ao.z, x1w = a.w + as.w*ao.w;
  float mcx = fminf(fmaxf(mu4.x, 0.5f), 1.5f);
  float mcy = fminf(fmaxf(mu4.y, 0.5f), 1.5f);
  float mcz = fminf(fmaxf(mu4.z, 0.5f), 1.5f);
  float mcw = fminf(fmaxf(mu4.w, 0.5f), 1.5f);
  float vnx = fminf(fmaxf(0.95f*vv.x - 0.3f*(x1x - mcx), -3.f), 3.f);
  float vny = fminf(fmaxf(0.95f*vv.y - 0.3f*(x1y - mcy), -3.f), 3.f);
  float vnz = fminf(fmaxf(0.95f*vv.z - 0.3f*(x1z - mcz), -3.f), 3.f);
  float vnw = fminf(fmaxf(0.95f*vv.w - 0.3f*(x1w - mcw), -3.f), 3.f);
  float4 x2 = {x1x + 0.01f*vnx, x1y + 0.01f*vny, x1z + 0.01f*vnz, x1w + 0.01f*vnw};
  float4 vn = {vnx, vny, vnz, vnw};
  *(float4*)(out + base) = x2;
  *(float4*)(out + (size_t)NTOK*NDIM + base) = vn;
  float ss = x2.x*x2.x + x2.y*x2.y + x2.z*x2.z + x2.w*x2.w;
  ss = wred64(ss);
  __shared__ float wsum[4];
  if ((t & 63) == 0) wsum[t >> 6] = ss;
  __syncthreads();
  float tot = wsum[0] + wsum[1] + wsum[2] + wsum[3];
  float rms = rsqrtf(tot * (1.0f/NDIM) + RMS_EPS);
  float4 m4 = {x2.x*rms, x2.y*rms, x2.z*rms, x2.w*rms};
  *(float4*)(mbuf + base) = m4;
}

// --------- K6a: token routing ---------
__global__ __launch_bounds__(256) void k_route(
    const int* __restrict__ eids, int* __restrict__ rowmap,
    int* __restrict__ tiletab, int* __restrict__ meta) {
  __shared__ int cnt[NEXP];
  __shared__ int ctr[NEXP];
  const int t = threadIdx.x;
  if (t < NEXP) cnt[t] = 0;
  __syncthreads();
  for (int i = t; i < NTOK; i += 256) atomicAdd(&cnt[eids[i]], 1);
  __syncthreads();
  if (t == 0) {
    int off = 0, tile = 0;
    for (int e = 0; e < NEXP; ++e) {
      ctr[e] = off;
      int nt_e = (cnt[e] + 63) >> 6;
      for (int j = 0; j < nt_e; ++j) { tiletab[2*tile] = e; tiletab[2*tile+1] = off + j*64; ++tile; }
      off += cnt[e];
      meta[1 + e] = off;
    }
    meta[0] = tile;
    for (int j = tile; j < MAXTILE; ++j) { tiletab[2*j] = -1; tiletab[2*j+1] = 0; }
  }
  __syncthreads();
  for (int i = t; i < NTOK; i += 256) {
    int e = eids[i];
    int slot = atomicAdd(&ctr[e], 1);
    rowmap[slot] = i;
  }
}

// --------- K6b: grouped GEMM1 ---------
__global__ __launch_bounds__(256) void k_moe_gemm1(
    const float* __restrict__ mbuf, const float* __restrict__ gate_up,
    const int* __restrict__ rowmap, const int* __restrict__ tiletab,
    const int* __restrict__ meta, float* __restrict__ hbuf) {
  const int e = tiletab[2*blockIdx.y];
  if (e < 0) return;
  const int slot0 = tiletab[2*blockIdx.y + 1];
  const int end = meta[1 + e];
  __shared__ float sA[16][68];
  __shared__ float sBg[16][68];
  __shared__ float sBu[16][68];
  const int t = threadIdx.x;
  const int tx = t & 15, ty = t >> 4;
  const int col0 = blockIdx.x * 64;
  const int lm = t >> 2, lk = (t & 3) * 4;
  const int kr = t >> 4, cc = (t & 15) * 4;
  const int slotA = slot0 + lm;
  const int tokA = (slotA < end) ? rowmap[slotA] : 0;
  const float* B = gate_up + (size_t)e * NDIM * (2*NINTER);
  float ag[4][4] = {};
  float au[4][4] = {};
  for (int k0 = 0; k0 < NDIM; k0 += 16) {
    float4 a4 = *(const float4*)(mbuf + (size_t)tokA*NDIM + k0 + lk);
    float4 bg = *(const float4*)(B + (size_t)(k0+kr)*(2*NINTER) + col0 + cc);
    float4 bu = *(const float4*)(B + (size_t)(k0+kr)*(2*NINTER) + NINTER + col0 + cc);
    __syncthreads();
    sA[lk+0][lm] = a4.x; sA[lk+1][lm] = a4.y; sA[lk+2][lm] = a4.z; sA[lk+3][lm] = a4.w;
    *(float4*)&sBg[kr][cc] = bg;
    *(float4*)&sBu[kr][cc] = bu;
    __syncthreads();
#pragma unroll
    for (int kk = 0; kk < 16; ++kk) {
      float4 av = *(const float4*)&sA[kk][ty*4];
      float4 bgv = *(const float4*)&sBg[kk][tx*4];
      float4 buv = *(const float4*)&sBu[kk][tx*4];
      ag[0][0] += av.x*bgv.x; ag[0][1] += av.x*bgv.y; ag[0][2] += av.x*bgv.z; ag[0][3] += av.x*bgv.w;
      ag[1][0] += av.y*bgv.x; ag[1][1] += av.y*bgv.y; ag[1][2] += av.y*bgv.z; ag[1][3] += av.y*bgv.w;
      ag[2][0] += av.z*bgv.x; ag[2][1] += av.z*bgv.y; ag[2][2] += av.z*bgv.z; ag[2][3] += av.z*bgv.w;
      ag[3][0] += av.w*bgv.x; ag[3][1] += av.w*bgv.y; ag[3][2] += av.w*bgv.z; ag[3][3] += av.w*bgv.w;
      au[0][0] += av.x*buv.x; au[0][1] += av.x*buv.y; au[0][2] += av.x*buv.z; au[0][3] += av.x*buv.w;
      au[1][0] += av.y*buv.x; au[1][1] += av.y*buv.y; au[1][2] += av.y*buv.z; au[1][3] += av.y*buv.w;
      au[2][0] += av.z*buv.x; au[2][1] += av.z*buv.y; au[2][2] += av.z*buv.z; au[2][3] += av.z*buv.w;
      au[3][0] += av.w*buv.x; au[3][1] += av.w*buv.y; au[3][2] += av.w*buv.z; au[3][3] += av.w*buv.w;
    }
  }
#pragma unroll
  for (int i = 0; i < 4; ++i) {
    if (slot0 + ty*4 + i < end) {
#pragma unroll
      for (int j = 0; j < 4; ++j) {
        float g = ag[i][j], u = au[i][j];
        float h = (g / (1.0f + __expf(-g))) * u;
        hbuf[(size_t)(slot0 + ty*4 + i)*NINTER + col0 + tx*4 + j] = h;
      }
    }
  }
}

// --------- K6c: grouped GEMM2 ---------
__global__ __launch_bounds__(256) void k_moe_gemm2(
    const float* __restrict__ hbuf, const float* __restrict__ down,
    const int* __restrict__ rowmap, const int* __restrict__ tiletab,
    const int* __restrict__ meta, const float* __restrict__ mscale,
    float* __restrict__ out) {
  const int e = tiletab[2*blockIdx.y];
  if (e < 0) return;
  const int slot0 = tiletab[2*blockIdx.y + 1];
  const int end = meta[1 + e];
  __shared__ float sA[16][68];
  __shared__ float sB[16][68];
  const int t = threadIdx.x;
  const int tx = t & 15, ty = t >> 4;
  const int col0 = blockIdx.x * 64;
  const int lm = t >> 2, lk = (t & 3) * 4;
  const int kr = t >> 4, cc = (t & 15) * 4;
  const float* B = down + (size_t)e * NINTER * NDIM;
  float acc[4][4] = {};
  for (int k0 = 0; k0 < NINTER; k0 += 16) {
    float4 a4 = *(const float4*)(hbuf + (size_t)(slot0 + lm)*NINTER + k0 + lk);
    float4 b4 = *(const float4*)(B + (size_t)(k0+kr)*NDIM + col0 + cc);
    __syncthreads();
    sA[lk+0][lm] = a4.x; sA[lk+1][lm] = a4.y; sA[lk+2][lm] = a4.z; sA[lk+3][lm] = a4.w;
    *(float4*)&sB[kr][cc] = b4;
    __syncthreads();
#pragma unroll
    for (int kk = 0; kk < 16; ++kk) {
      float4 av = *(const float4*)&sA[kk][ty*4];
      float4 bv = *(const float4*)&sB[kk][tx*4];
      acc[0][0] += av.x*bv.x; acc[0][1] += av.x*bv.y; acc[0][2] += av.x*bv.z; acc[0][3] += av.x*bv.w;
      acc[1][0] += av.y*bv.x; acc[1][1] += av.y*bv.y; acc[1][2] += av.y*bv.z; acc[1][3] += av.y*bv.w;
      acc[2][0] += av.z*bv.x; acc[2][1] += av.z*bv.y; acc[2][2] += av.z*bv.z; acc[2][3] += av.z*bv.w;
      acc[3][0] += av.w*bv.x; acc[3][1] += av.w*bv.y; acc[3][2] += av.w*bv.z; acc[3][3] += av.w*bv.w;
    }
  }
#pragma unroll
  for (int i = 0; i < 4; ++i) {
    int slot = slot0 + ty*4 + i;
    if (slot < end) {
      int tok = rowmap[slot];
      float* op = out + (size_t)tok*NDIM + col0 + tx*4;
      const float* sp = mscale + col0 + tx*4;
#pragma unroll
      for (int j = 0; j < 4; ++j) op[j] += sp[j] * acc[i][j];
    }
  }
}

extern "C" void kernel_launch(void* const* d_in, const int* in_sizes, int n_in,
                              void* d_out, int out_size, void* d_ws, size_t ws_size,
                              hipStream_t stream) {
  const float* x      = (const float*)d_in[0];
  const float* x0     = (const float*)d_in[1];
  const float* vel    = (const float*)d_in[2];
  const float* rmix   = (const float*)d_in[3];
  const float* ascale = (const float*)d_in[4];
  const float* mscale = (const float*)d_in[5];
  const float* cq_w   = (const float*)d_in[6];
  const float* ck_w   = (const float*)d_in[7];
  const float* cv_w   = (const float*)d_in[8];
  const float* proj_w = (const float*)d_in[9];
  const float* q_gain = (const float*)d_in[10];
  const float* mu     = (const float*)d_in[11];
  const float* gate_up= (const float*)d_in[12];
  const float* down   = (const float*)d_in[13];
  const int*   eids   = (const int*)d_in[14];
  float* out = (float*)d_out;
  float* ws  = (float*)d_ws;

  const size_t M4 = (size_t)NTOK * NDIM;      // 4M floats
  float* xr   = ws;                           // [0, 4M)
  float* nbuf = ws + M4;                      // [4M, 8M): n -> y -> mbuf
  float* regC = ws + 2*M4;                    // [8M, 12M): bf16 pack, then aout, then routing
  short* qb  = (short*)regC;                  // NTOK*NDIM bf16 (2M floats)
  short* kb  = (short*)(regC + M4/2);         // NTOK*KVD bf16 (0.5M floats)
  short* vb  = (short*)(regC + M4/2 + M4/8);  // NTOK*KVD bf16
  short* vbT = (short*)(regC + M4/2 + M4/4);  // NTOK*KVD bf16 transposed
  float* ybuf = nbuf;
  float* aout = regC;     // after attention, bf16 buffers dead
  float* mbuf = nbuf;     // after proj, y dead
  float* hbuf = xr;       // after fuse_vel, xr dead
  int* rowmap = (int*)regC;               // after fuse_vel, aout dead
  int* tiletab = rowmap + NTOK;
  int* meta = tiletab + 2*MAXTILE;

  k_resid_rms<<<NTOK, 256, 0, stream>>>(x, x0, rmix, xr, nbuf);
  k_gemm_nt<short><<<dim3(NDIM/64, NTOK/64), 256, 0, stream>>>(nbuf, cq_w, qb, NTOK, NDIM, NDIM);
  k_gemm_nt<short><<<dim3(KVD/64,  NTOK/64), 256, 0, stream>>>(nbuf, ck_w, kb, NTOK, KVD,  NDIM);
  k_gemm_nt<short><<<dim3(KVD/64,  NTOK/64), 256, 0, stream>>>(nbuf, cv_w, vb, NTOK, KVD,  NDIM);
  k_qk_norm_rope<<<NTOK, 256, 0, stream>>>(qb, kb, q_gain);
  k_transpose_v<<<NBATCH*NKVH*(NSEQ/64), 256, 0, stream>>>(vb, vbT);
  k_attn_mfma<<<NBATCH*NHEAD*(NSEQ/64), 256, 0, stream>>>(qb, kb, vbT, ybuf);
  k_gemm_nt<float><<<dim3(NDIM/64, NTOK/64), 256, 0, stream>>>(ybuf, proj_w, aout, NTOK, NDIM, NDIM);
  k_fuse_vel<<<NTOK, 256, 0, stream>>>(xr, aout, vel, ascale, mu, out, mbuf);
  k_route<<<1, 256, 0, stream>>>(eids, rowmap, tiletab, meta);
  k_moe_gemm1<<<dim3(NINTER/64, MAXTILE), 256, 0, stream>>>(mbuf, gate_up, rowmap, tiletab, meta, hbuf);
  k_moe_gemm2<<<dim3(NDIM/64, MAXTILE), 256, 0, stream>>>(hbuf, down, rowmap, tiletab, meta, mscale, out);
}

// Round 5
// 299.572 us; speedup vs baseline: 12.0449x; 2.6760x over previous
//
#include <hip/hip_runtime.h>
#include <hip/hip_bf16.h>
#include <math.h>

#define NBATCH 2
#define NSEQ   2048
#define NDIM   1024
#define NHEAD  16
#define NKVH   4
#define HDIM   64
#define KVD    256
#define NEXP   8
#define NINTER 512
#define NTOK   (NBATCH*NSEQ)
#define QKVN   1536
#define MAXTILE 40
#define RMS_EPS 1.1920929e-07f
#define LN_10000 9.210340371976184f

typedef __attribute__((ext_vector_type(8))) short bf16x8;
typedef __attribute__((ext_vector_type(4))) short short4v;
typedef __attribute__((ext_vector_type(4))) float f32x4;

__device__ __forceinline__ short f2b(float f) {
  unsigned u = __builtin_bit_cast(unsigned, f);
  unsigned r = (u + 0x7fffu + ((u >> 16) & 1u)) >> 16;  // RNE
  return (short)r;
}
__device__ __forceinline__ float b2f(short s) {
  unsigned u = ((unsigned)(unsigned short)s) << 16;
  return __builtin_bit_cast(float, u);
}
__device__ __forceinline__ void load_lds16(const short* g, short* l) {
  __builtin_amdgcn_global_load_lds((const __attribute__((address_space(1))) void*)g,
                                   (__attribute__((address_space(3))) void*)l, 16, 0, 0);
}

__device__ __forceinline__ float wred64(float v) {
#pragma unroll
  for (int m = 32; m >= 1; m >>= 1) v += __shfl_xor(v, m);
  return v;
}

// ---------------- W0: cast attention weights to bf16 (wqkv concat + wproj) ----------------
__global__ __launch_bounds__(256) void k_w_cast(
    const float* __restrict__ cq, const float* __restrict__ ck,
    const float* __restrict__ cv, const float* __restrict__ pw,
    short* __restrict__ wqkv, short* __restrict__ wproj) {
  const int row = blockIdx.x;
  const int c = threadIdx.x * 4;
  const float* src; short* dst;
  if (row < 1024)      { src = cq + (size_t)row*NDIM;        dst = wqkv + (size_t)row*NDIM; }
  else if (row < 1280) { src = ck + (size_t)(row-1024)*NDIM; dst = wqkv + (size_t)row*NDIM; }
  else if (row < 1536) { src = cv + (size_t)(row-1280)*NDIM; dst = wqkv + (size_t)row*NDIM; }
  else                 { src = pw + (size_t)(row-1536)*NDIM; dst = wproj + (size_t)(row-1536)*NDIM; }
  float4 v = *(const float4*)(src + c);
  short4v o = {f2b(v.x), f2b(v.y), f2b(v.z), f2b(v.w)};
  *(short4v*)(dst + c) = o;
}

// ---------------- W1: per-expert transpose fp32 [KIN][NIN] -> bf16 [NIN][KIN] ----------------
__global__ __launch_bounds__(256) void k_w_transpose(
    const float* __restrict__ in, short* __restrict__ outp, int KIN, int NIN) {
  __shared__ short T[64*66];
  const int kt = blockIdx.x, nt = blockIdx.y, e = blockIdx.z;
  const float* ie = in + (size_t)e*KIN*NIN + (size_t)(kt*64)*NIN + nt*64;
  short* oe = outp + (size_t)e*NIN*KIN + (size_t)(nt*64)*KIN + kt*64;
  const int t = threadIdx.x;
  const int r = t >> 4, c = (t & 15) * 4;
#pragma unroll
  for (int p = 0; p < 4; ++p) {
    float4 v = *(const float4*)(ie + (size_t)(p*16 + r)*NIN + c);
    T[(p*16 + r)*66 + c + 0] = f2b(v.x);
    T[(p*16 + r)*66 + c + 1] = f2b(v.y);
    T[(p*16 + r)*66 + c + 2] = f2b(v.z);
    T[(p*16 + r)*66 + c + 3] = f2b(v.w);
  }
  __syncthreads();
#pragma unroll
  for (int p = 0; p < 4; ++p) {
    int rr = p*16 + r;
    short4v o = {T[(c+0)*66 + rr], T[(c+1)*66 + rr], T[(c+2)*66 + rr], T[(c+3)*66 + rr]};
    *(short4v*)(oe + (size_t)rr*KIN + c) = o;
  }
}

// ---------------- K1: xr(bf16) = mix; n(bf16) = rmsnorm ----------------
__global__ __launch_bounds__(256) void k_resid_rms(
    const float* __restrict__ x, const float* __restrict__ x0,
    const float* __restrict__ rmix, short* __restrict__ xr, short* __restrict__ nrm) {
  const int row = blockIdx.x;
  const int t = threadIdx.x;
  const int d = t * 4;
  const size_t base = (size_t)row * NDIM + d;
  float4 a  = *(const float4*)(x  + base);
  float4 b  = *(const float4*)(x0 + base);
  float4 m0 = *(const float4*)(rmix + d);
  float4 m1 = *(const float4*)(rmix + NDIM + d);
  float4 r;
  r.x = m0.x*a.x + m1.x*b.x;
  r.y = m0.y*a.y + m1.y*b.y;
  r.z = m0.z*a.z + m1.z*b.z;
  r.w = m0.w*a.w + m1.w*b.w;
  float ss = r.x*r.x + r.y*r.y + r.z*r.z + r.w*r.w;
  ss = wred64(ss);
  __shared__ float wsum[4];
  if ((t & 63) == 0) wsum[t >> 6] = ss;
  __syncthreads();
  float tot = wsum[0] + wsum[1] + wsum[2] + wsum[3];
  float rms = rsqrtf(tot * (1.0f/NDIM) + RMS_EPS);
  short4v xo = {f2b(r.x), f2b(r.y), f2b(r.z), f2b(r.w)};
  short4v no = {f2b(r.x*rms), f2b(r.y*rms), f2b(r.z*rms), f2b(r.w*rms)};
  *(short4v*)(xr + base) = xo;
  *(short4v*)(nrm + base) = no;
}

// ---------------- K2: MFMA GEMM 128x128, BK=32, global_load_lds staging ----------------
// C[M,N] = A[M,K](bf16 row-major) . B[N,K](bf16 row-major)^T
// MODE 0: plain rows, bf16 out. MODE 1: gather-A rowmap, bf16 out, row<end guard.
// MODE 2: compact-A, scatter-add fp32 out with mscale, row<end guard.
template <int MODE>
__global__ __launch_bounds__(256) void k_gemm_mfma(
    const short* __restrict__ A, int lda,
    const short* __restrict__ Bw, int K, int N,
    short* __restrict__ Cb, float* __restrict__ Cf, int ldc,
    const int* __restrict__ rowmap, const int* __restrict__ tiletab,
    const int* __restrict__ meta, const float* __restrict__ mscale) {
  __shared__ short sA[128*32];
  __shared__ short sB[128*32];
  int row0, end = 0x7fffffff, e = 0;
  if (MODE == 0) {
    row0 = blockIdx.y * 128;
  } else {
    e = tiletab[2*blockIdx.y];
    if (e < 0) return;
    row0 = tiletab[2*blockIdx.y + 1];
    end = meta[1 + e];
  }
  const int t = threadIdx.x;
  const int w = t >> 6, l = t & 63;
  const int wr = (w >> 1) * 64, wc = (w & 1) * 64;
  const int lrow = l & 15, lk8 = (l >> 4) * 8;
  const int srow0 = w*16 + (l >> 2);    // staging row within 64-row half
  const int scol = (l & 3) * 8;         // staging col (8 bf16 = 16 B)
  const short* Bp = Bw + (size_t)e * N * K + (size_t)(blockIdx.x * 128) * K;
  const short* gA0;
  const short* gA1;
  if (MODE == 1) {
    int s0 = row0 + srow0;      if (s0 >= NTOK) s0 = NTOK - 1;
    int s1 = row0 + 64 + srow0; if (s1 >= NTOK) s1 = NTOK - 1;
    gA0 = A + (size_t)rowmap[s0] * lda + scol;
    gA1 = A + (size_t)rowmap[s1] * lda + scol;
  } else {
    gA0 = A + (size_t)(row0 + srow0) * lda + scol;
    gA1 = A + (size_t)(row0 + 64 + srow0) * lda + scol;
  }
  const short* gB0 = Bp + (size_t)srow0 * K + scol;
  const short* gB1 = Bp + (size_t)(64 + srow0) * K + scol;
  short* lA0 = sA + (w*16)*32;          // wave-uniform LDS bases
  short* lA1 = sA + (64 + w*16)*32;
  short* lB0 = sB + (w*16)*32;
  short* lB1 = sB + (64 + w*16)*32;
  f32x4 acc[4][4];
#pragma unroll
  for (int m = 0; m < 4; ++m)
#pragma unroll
    for (int n = 0; n < 4; ++n) acc[m][n] = 0.f;
  for (int k0 = 0; k0 < K; k0 += 32) {
    __syncthreads();
    load_lds16(gA0, lA0);
    load_lds16(gA1, lA1);
    load_lds16(gB0, lB0);
    load_lds16(gB1, lB1);
    gA0 += 32; gA1 += 32; gB0 += 32; gB1 += 32;
    __syncthreads();
    bf16x8 af[4], bfr[4];
#pragma unroll
    for (int m = 0; m < 4; ++m)
      af[m] = *(const bf16x8*)&sA[(wr + m*16 + lrow)*32 + lk8];
#pragma unroll
    for (int n = 0; n < 4; ++n)
      bfr[n] = *(const bf16x8*)&sB[(wc + n*16 + lrow)*32 + lk8];
#pragma unroll
    for (int m = 0; m < 4; ++m)
#pragma unroll
      for (int n = 0; n < 4; ++n)
        acc[m][n] = __builtin_amdgcn_mfma_f32_16x16x32_bf16(af[m], bfr[n], acc[m][n], 0, 0, 0);
  }
  const int col0 = blockIdx.x * 128;
  if (MODE <= 1) {
#pragma unroll
    for (int m = 0; m < 4; ++m) {
#pragma unroll
      for (int r = 0; r < 4; ++r) {
        int rr = row0 + wr + m*16 + (l >> 4)*4 + r;
        if (rr < end) {
#pragma unroll
          for (int n = 0; n < 4; ++n)
            Cb[(size_t)rr * ldc + col0 + wc + n*16 + lrow] = f2b(acc[m][n][r]);
        }
      }
    }
  } else {
#pragma unroll
    for (int m = 0; m < 4; ++m) {
#pragma unroll
      for (int r = 0; r < 4; ++r) {
        int slot = row0 + wr + m*16 + (l >> 4)*4 + r;
        if (slot < end) {
          int tok = rowmap[slot];
#pragma unroll
          for (int n = 0; n < 4; ++n) {
            int cc = col0 + wc + n*16 + lrow;
            Cf[(size_t)tok * ldc + cc] += mscale[cc] * acc[m][n][r];
          }
        }
      }
    }
  }
}

// --------- K3: per-head rmsnorm + rope (+0.125*q_gain folded), bf16 in-place on qkv ---------
__global__ __launch_bounds__(256) void k_qk_norm_rope(
    short* __restrict__ qkv, const float* __restrict__ q_gain) {
  const int row = blockIdx.x;          // b*S+s
  const int t = threadIdx.x;
  const int w = t >> 6, lane = t & 63;
  const int s = row & (NSEQ - 1);
  const int fi = lane & 31;
  const float fr = (float)s * expf(-(float)fi * (LN_10000 / 32.0f));
  const float co = cosf(fr), si = sinf(fr);
#pragma unroll
  for (int h = w; h < NHEAD; h += 4) {
    short* p = qkv + (size_t)row*QKVN + h*HDIM + lane;
    float v = b2f(*p);
    float ssum = wred64(v*v);
    float rr = rsqrtf(ssum * (1.0f/HDIM) + RMS_EPS);
    float vn = v * rr;
    float partner = __shfl_xor(vn, 32);
    float o = (lane < 32) ? (vn*co + partner*si) : (vn*co - partner*si);
    *p = f2b(o * q_gain[h] * 0.125f);
  }
  if (w < NKVH) {
    short* p = qkv + (size_t)row*QKVN + 1024 + w*HDIM + lane;
    float v = b2f(*p);
    float ssum = wred64(v*v);
    float rr = rsqrtf(ssum * (1.0f/HDIM) + RMS_EPS);
    float vn = v * rr;
    float partner = __shfl_xor(vn, 32);
    float o = (lane < 32) ? (vn*co + partner*si) : (vn*co - partner*si);
    *p = f2b(o);
  }
}

// --------- K3b: V transpose to [b][kh][dim][seq] bf16 ---------
__global__ __launch_bounds__(256) void k_transpose_v(
    const short* __restrict__ qkv, short* __restrict__ vbT) {
  __shared__ short T[64*72];
  const int blk = blockIdx.x;
  const int st = blk & 31, kh = (blk >> 5) & 3, b = blk >> 7;
  const int t = threadIdx.x;
#pragma unroll
  for (int i = 0; i < 2; ++i) {
    int c = t + i*256;
    int s = c >> 3, d0 = (c & 7) * 8;
    bf16x8 v = *(const bf16x8*)(qkv + (size_t)(b*NSEQ + st*64 + s)*QKVN + 1280 + kh*HDIM + d0);
#pragma unroll
    for (int j = 0; j < 8; ++j) T[(d0 + j)*72 + s] = v[j];
  }
  __syncthreads();
#pragma unroll
  for (int i = 0; i < 2; ++i) {
    int c = t + i*256;
    int d = c >> 3, s0 = (c & 7) * 8;
    *(bf16x8*)(vbT + (size_t)((b*NKVH + kh)*HDIM + d)*NSEQ + st*64 + s0) = *(bf16x8*)&T[d*72 + s0];
  }
}

// ---------------- K4: causal flash attention, MFMA bf16 16x16x32 ----------------
__global__ __launch_bounds__(256) void k_attn_mfma(
    const short* __restrict__ qkv, const short* __restrict__ vbT, short* __restrict__ y) {
  __shared__ short Ks[64*72];   // [key][dim]
  __shared__ short Vt[64*72];   // [dim][key]
  __shared__ short Ps[64*72];   // [qrow][key], per-wave-private rows
  const int t = threadIdx.x;
  const int l = t & 63, w = t >> 6;
  const int lrow = l & 15, lk8 = (l >> 4) * 8;
  const int bid = blockIdx.x;
  const int qt = bid & 31, h = (bid >> 5) & 15, b = bid >> 9;
  const int kh = h >> 2;
  const int qrow_g = b*NSEQ + qt*64 + w*16 + lrow;
  bf16x8 qf0 = *(const bf16x8*)(qkv + (size_t)qrow_g*QKVN + h*HDIM + lk8);
  bf16x8 qf1 = *(const bf16x8*)(qkv + (size_t)qrow_g*QKVN + h*HDIM + 32 + lk8);
  float m_i[4], l_i[4];
  f32x4 O[4];
#pragma unroll
  for (int r = 0; r < 4; ++r) { m_i[r] = -INFINITY; l_i[r] = 0.f; }
#pragma unroll
  for (int db = 0; db < 4; ++db)
#pragma unroll
    for (int r = 0; r < 4; ++r) O[db][r] = 0.f;

  for (int kt = 0; kt <= qt; ++kt) {
    __syncthreads();
#pragma unroll
    for (int i = 0; i < 2; ++i) {
      int c = t + i*256;
      int r0 = c >> 3, d0 = (c & 7) * 8;
      *(bf16x8*)&Ks[r0*72 + d0] =
          *(const bf16x8*)(qkv + (size_t)(b*NSEQ + kt*64 + r0)*QKVN + 1024 + kh*HDIM + d0);
      *(bf16x8*)&Vt[r0*72 + d0] =
          *(const bf16x8*)(vbT + (size_t)((b*NKVH + kh)*HDIM + r0)*NSEQ + kt*64 + d0);
    }
    __syncthreads();
    f32x4 sc[4];
#pragma unroll
    for (int nb = 0; nb < 4; ++nb)
#pragma unroll
      for (int r = 0; r < 4; ++r) sc[nb][r] = 0.f;
#pragma unroll
    for (int nb = 0; nb < 4; ++nb) {
      bf16x8 kf0 = *(const bf16x8*)&Ks[(nb*16 + lrow)*72 + lk8];
      bf16x8 kf1 = *(const bf16x8*)&Ks[(nb*16 + lrow)*72 + 32 + lk8];
      sc[nb] = __builtin_amdgcn_mfma_f32_16x16x32_bf16(qf0, kf0, sc[nb], 0, 0, 0);
      sc[nb] = __builtin_amdgcn_mfma_f32_16x16x32_bf16(qf1, kf1, sc[nb], 0, 0, 0);
    }
    if (kt == qt) {
#pragma unroll
      for (int nb = 0; nb < 4; ++nb)
#pragma unroll
        for (int r = 0; r < 4; ++r)
          if (nb*16 + lrow > w*16 + (l >> 4)*4 + r) sc[nb][r] = -INFINITY;
    }
#pragma unroll
    for (int r = 0; r < 4; ++r) {
      float rm = fmaxf(fmaxf(sc[0][r], sc[1][r]), fmaxf(sc[2][r], sc[3][r]));
      rm = fmaxf(rm, __shfl_xor(rm, 1));
      rm = fmaxf(rm, __shfl_xor(rm, 2));
      rm = fmaxf(rm, __shfl_xor(rm, 4));
      rm = fmaxf(rm, __shfl_xor(rm, 8));
      float mn = fmaxf(m_i[r], rm);
      float fac = __expf(m_i[r] - mn);
      float rs = 0.f;
#pragma unroll
      for (int nb = 0; nb < 4; ++nb) {
        float p = __expf(sc[nb][r] - mn);
        sc[nb][r] = p;
        rs += p;
      }
      rs += __shfl_xor(rs, 1);
      rs += __shfl_xor(rs, 2);
      rs += __shfl_xor(rs, 4);
      rs += __shfl_xor(rs, 8);
      l_i[r] = l_i[r]*fac + rs;
      m_i[r] = mn;
#pragma unroll
      for (int db = 0; db < 4; ++db) O[db][r] *= fac;
    }
#pragma unroll
    for (int nb = 0; nb < 4; ++nb)
#pragma unroll
      for (int r = 0; r < 4; ++r)
        Ps[(w*16 + (l >> 4)*4 + r)*72 + nb*16 + lrow] = f2b(sc[nb][r]);
    bf16x8 pf0 = *(const bf16x8*)&Ps[(w*16 + lrow)*72 + lk8];
    bf16x8 pf1 = *(const bf16x8*)&Ps[(w*16 + lrow)*72 + 32 + lk8];
#pragma unroll
    for (int db = 0; db < 4; ++db) {
      bf16x8 vf0 = *(const bf16x8*)&Vt[(db*16 + lrow)*72 + lk8];
      bf16x8 vf1 = *(const bf16x8*)&Vt[(db*16 + lrow)*72 + 32 + lk8];
      O[db] = __builtin_amdgcn_mfma_f32_16x16x32_bf16(pf0, vf0, O[db], 0, 0, 0);
      O[db] = __builtin_amdgcn_mfma_f32_16x16x32_bf16(pf1, vf1, O[db], 0, 0, 0);
    }
  }
#pragma unroll
  for (int r = 0; r < 4; ++r) {
    float inv = 1.0f / l_i[r];
    int rowo = b*NSEQ + qt*64 + w*16 + (l >> 4)*4 + r;
#pragma unroll
    for (int db = 0; db < 4; ++db)
      y[(size_t)rowo*NDIM + h*HDIM + db*16 + lrow] = f2b(O[db][r] * inv);
  }
}

// --------- K5: x2/v_next -> out(f32) ; mbuf = rmsnorm(x2) bf16 ---------
__global__ __launch_bounds__(256) void k_fuse_vel(
    const short* __restrict__ xr, const short* __restrict__ aout,
    const float* __restrict__ vel, const float* __restrict__ ascale,
    const float* __restrict__ mu, float* __restrict__ out, short* __restrict__ mbuf) {
  const int row = blockIdx.x;
  const int t = threadIdx.x;
  const int d = t * 4;
  const size_t base = (size_t)row * NDIM + d;
  short4v a4 = *(const short4v*)(xr + base);
  short4v o4 = *(const short4v*)(aout + base);
  float4 vv = *(const float4*)(vel + base);
  float4 as = *(const float4*)(ascale + d);
  float4 mu4 = *(const float4*)(mu + d);
  float xs[4], vns[4];
  const float asl[4] = {as.x, as.y, as.z, as.w};
  const float mul[4] = {mu4.x, mu4.y, mu4.z, mu4.w};
  const float vvl[4] = {vv.x, vv.y, vv.z, vv.w};
#pragma unroll
  for (int i = 0; i < 4; ++i) {
    float x1 = b2f(a4[i]) + asl[i] * b2f(o4[i]);
    float muc = fminf(fmaxf(mul[i], 0.5f), 1.5f);
    float vn = fminf(fmaxf(0.95f*vvl[i] - 0.3f*(x1 - muc), -3.f), 3.f);
    xs[i] = x1 + 0.01f*vn;
    vns[i] = vn;
  }
  float4 x2 = {xs[0], xs[1], xs[2], xs[3]};
  float4 vnq = {vns[0], vns[1], vns[2], vns[3]};
  *(float4*)(out + base) = x2;
  *(float4*)(out + (size_t)NTOK*NDIM + base) = vnq;
  float ss = xs[0]*xs[0] + xs[1]*xs[1] + xs[2]*xs[2] + xs[3]*xs[3];
  ss = wred64(ss);
  __shared__ float wsum[4];
  if ((t & 63) == 0) wsum[t >> 6] = ss;
  __syncthreads();
  float tot = wsum[0] + wsum[1] + wsum[2] + wsum[3];
  float rms = rsqrtf(tot * (1.0f/NDIM) + RMS_EPS);
  short4v m4 = {f2b(xs[0]*rms), f2b(xs[1]*rms), f2b(xs[2]*rms), f2b(xs[3]*rms)};
  *(short4v*)(mbuf + base) = m4;
}

// --------- K6a: token routing (128-row tiles) ---------
__global__ __launch_bounds__(256) void k_route(
    const int* __restrict__ eids, int* __restrict__ rowmap,
    int* __restrict__ tiletab, int* __restrict__ meta) {
  __shared__ int cnt[NEXP];
  __shared__ int ctr[NEXP];
  const int t = threadIdx.x;
  if (t < NEXP) cnt[t] = 0;
  __syncthreads();
  for (int i = t; i < NTOK; i += 256) atomicAdd(&cnt[eids[i]], 1);
  __syncthreads();
  if (t == 0) {
    int off = 0, tile = 0;
    for (int e = 0; e < NEXP; ++e) {
      ctr[e] = off;
      int nt_e = (cnt[e] + 127) >> 7;
      for (int j = 0; j < nt_e; ++j) { tiletab[2*tile] = e; tiletab[2*tile+1] = off + j*128; ++tile; }
      off += cnt[e];
      meta[1 + e] = off;
    }
    meta[0] = tile;
    for (int j = tile; j < MAXTILE; ++j) { tiletab[2*j] = -1; tiletab[2*j+1] = 0; }
  }
  __syncthreads();
  for (int i = t; i < NTOK; i += 256) {
    int e = eids[i];
    int slot = atomicAdd(&ctr[e], 1);
    rowmap[slot] = i;
  }
}

// --------- K6b: h = silu(g)*u from gu rows ---------
__global__ __launch_bounds__(256) void k_silu(
    const short* __restrict__ gu, short* __restrict__ hb) {
  int gid = blockIdx.x * 256 + threadIdx.x;
  int row = gid >> 7, c4 = (gid & 127) * 4;
  short4v g = *(const short4v*)(gu + (size_t)row*1024 + c4);
  short4v u = *(const short4v*)(gu + (size_t)row*1024 + 512 + c4);
  short4v o;
#pragma unroll
  for (int i = 0; i < 4; ++i) {
    float gf = b2f(g[i]), uf = b2f(u[i]);
    o[i] = f2b(gf / (1.0f + __expf(-gf)) * uf);
  }
  *(short4v*)(hb + (size_t)row*512 + c4) = o;
}

extern "C" void kernel_launch(void* const* d_in, const int* in_sizes, int n_in,
                              void* d_out, int out_size, void* d_ws, size_t ws_size,
                              hipStream_t stream) {
  const float* x      = (const float*)d_in[0];
  const float* x0     = (const float*)d_in[1];
  const float* vel    = (const float*)d_in[2];
  const float* rmix   = (const float*)d_in[3];
  const float* ascale = (const float*)d_in[4];
  const float* mscale = (const float*)d_in[5];
  const float* cq_w   = (const float*)d_in[6];
  const float* ck_w   = (const float*)d_in[7];
  const float* cv_w   = (const float*)d_in[8];
  const float* proj_w = (const float*)d_in[9];
  const float* q_gain = (const float*)d_in[10];
  const float* mu     = (const float*)d_in[11];
  const float* gate_up= (const float*)d_in[12];
  const float* down   = (const float*)d_in[13];
  const int*   eids   = (const int*)d_in[14];
  float* out = (float*)d_out;
  char* base = (char*)d_ws;

  // ws layout (52 MB total, sequential-reuse verified):
  // [0,3)    wqkv bf16 [1536][1024]
  // [3,5)    wproj bf16 [1024][1024]
  // [5,6)    rowmap/tiletab/meta
  // [6,22)   wgu_t bf16 [8][1024][1024]  -> hbuf bf16 [4096][512] after gemm1
  // [22,30)  xr bf16 [4096][1024]        -> gu bf16 [4096][1024] after fuse_vel
  // [30,38)  nbuf bf16 -> ybuf bf16 -> mbuf bf16 -> wdn_t bf16 [8][1024][512]
  // [38,50)  qkv bf16 [4096][1536]       -> aout bf16 [4096][1024] after attn
  // [50,52)  vbT bf16 [2][4][64][2048]
  const size_t MB = 1024*1024;
  short* wqkv  = (short*)base;
  short* wproj = (short*)(base + 3*MB);
  int*   rowmap  = (int*)(base + 5*MB);
  int*   tiletab = rowmap + NTOK;
  int*   meta    = tiletab + 2*MAXTILE;
  short* wgu_t = (short*)(base + 6*MB);
  short* hbuf  = wgu_t;
  short* xr    = (short*)(base + 22*MB);
  short* gu    = xr;
  short* nbuf  = (short*)(base + 30*MB);
  short* ybuf  = nbuf;
  short* mbuf  = nbuf;
  short* wdn_t = nbuf;
  short* qkv   = (short*)(base + 38*MB);
  short* aout  = qkv;
  short* vbT   = (short*)(base + 50*MB);

  k_w_cast<<<2560, 256, 0, stream>>>(cq_w, ck_w, cv_w, proj_w, wqkv, wproj);
  k_w_transpose<<<dim3(16, 16, 8), 256, 0, stream>>>(gate_up, wgu_t, 1024, 1024);
  k_resid_rms<<<NTOK, 256, 0, stream>>>(x, x0, rmix, xr, nbuf);
  k_gemm_mfma<0><<<dim3(QKVN/128, NTOK/128), 256, 0, stream>>>(
      nbuf, NDIM, wqkv, NDIM, QKVN, qkv, nullptr, QKVN, nullptr, nullptr, nullptr, nullptr);
  k_qk_norm_rope<<<NTOK, 256, 0, stream>>>(qkv, q_gain);
  k_transpose_v<<<NBATCH*NKVH*(NSEQ/64), 256, 0, stream>>>(qkv, vbT);
  k_attn_mfma<<<NBATCH*NHEAD*(NSEQ/64), 256, 0, stream>>>(qkv, vbT, ybuf);
  k_gemm_mfma<0><<<dim3(NDIM/128, NTOK/128), 256, 0, stream>>>(
      ybuf, NDIM, wproj, NDIM, NDIM, aout, nullptr, NDIM, nullptr, nullptr, nullptr, nullptr);
  k_fuse_vel<<<NTOK, 256, 0, stream>>>(xr, aout, vel, ascale, mu, out, mbuf);
  k_route<<<1, 256, 0, stream>>>(eids, rowmap, tiletab, meta);
  k_gemm_mfma<1><<<dim3(1024/128, MAXTILE), 256, 0, stream>>>(
      mbuf, NDIM, wgu_t, NDIM, 1024, gu, nullptr, 1024, rowmap, tiletab, meta, nullptr);
  k_w_transpose<<<dim3(8, 16, 8), 256, 0, stream>>>(down, wdn_t, 512, 1024);
  k_silu<<<(NTOK*512)/(4*256), 256, 0, stream>>>(gu, hbuf);
  k_gemm_mfma<2><<<dim3(NDIM/128, MAXTILE), 256, 0, stream>>>(
      hbuf, NINTER, wdn_t, NINTER, NDIM, nullptr, out, NDIM, rowmap, tiletab, meta, mscale);
}

// Round 6
// 262.550 us; speedup vs baseline: 13.7433x; 1.1410x over previous
//
#include <hip/hip_runtime.h>
#include <hip/hip_bf16.h>
#include <math.h>

#define NBATCH 2
#define NSEQ   2048
#define NDIM   1024
#define NHEAD  16
#define NKVH   4
#define HDIM   64
#define KVD    256
#define NEXP   8
#define NINTER 512
#define NTOK   (NBATCH*NSEQ)
#define QKVN   1536
#define MAXTILE 40
#define RMS_EPS 1.1920929e-07f
#define LN_10000 9.210340371976184f
#define QSCALE (0.125f * 1.44269504088896f)   // 1/sqrt(64) * log2(e), folded into Q

typedef __attribute__((ext_vector_type(8))) short bf16x8;
typedef __attribute__((ext_vector_type(4))) short short4v;
typedef __attribute__((ext_vector_type(4))) float f32x4;

__device__ __forceinline__ short f2b(float f) {
  unsigned u = __builtin_bit_cast(unsigned, f);
  unsigned r = (u + 0x7fffu + ((u >> 16) & 1u)) >> 16;  // RNE
  return (short)r;
}
__device__ __forceinline__ float b2f(short s) {
  unsigned u = ((unsigned)(unsigned short)s) << 16;
  return __builtin_bit_cast(float, u);
}
__device__ __forceinline__ float ex2(float x) {   // 2^x via v_exp_f32
  float r; asm("v_exp_f32 %0, %1" : "=v"(r) : "v"(x)); return r;
}
__device__ __forceinline__ void load_lds16(const short* g, short* l) {
  __builtin_amdgcn_global_load_lds((const __attribute__((address_space(1))) void*)g,
                                   (__attribute__((address_space(3))) void*)l, 16, 0, 0);
}

__device__ __forceinline__ float wred64(float v) {
#pragma unroll
  for (int m = 32; m >= 1; m >>= 1) v += __shfl_xor(v, m);
  return v;
}

// ---------------- W0: cast attention weights to bf16 (wqkv concat + wproj) ----------------
__global__ __launch_bounds__(256) void k_w_cast(
    const float* __restrict__ cq, const float* __restrict__ ck,
    const float* __restrict__ cv, const float* __restrict__ pw,
    short* __restrict__ wqkv, short* __restrict__ wproj) {
  const int row = blockIdx.x;
  const int c = threadIdx.x * 4;
  const float* src; short* dst;
  if (row < 1024)      { src = cq + (size_t)row*NDIM;        dst = wqkv + (size_t)row*NDIM; }
  else if (row < 1280) { src = ck + (size_t)(row-1024)*NDIM; dst = wqkv + (size_t)row*NDIM; }
  else if (row < 1536) { src = cv + (size_t)(row-1280)*NDIM; dst = wqkv + (size_t)row*NDIM; }
  else                 { src = pw + (size_t)(row-1536)*NDIM; dst = wproj + (size_t)(row-1536)*NDIM; }
  float4 v = *(const float4*)(src + c);
  short4v o = {f2b(v.x), f2b(v.y), f2b(v.z), f2b(v.w)};
  *(short4v*)(dst + c) = o;
}

// ---------------- W1: per-expert transpose fp32 [KIN][NIN] -> bf16 [NIN][KIN] ----------------
__global__ __launch_bounds__(256) void k_w_transpose(
    const float* __restrict__ in, short* __restrict__ outp, int KIN, int NIN) {
  __shared__ short T[64*66];
  const int kt = blockIdx.x, nt = blockIdx.y, e = blockIdx.z;
  const float* ie = in + (size_t)e*KIN*NIN + (size_t)(kt*64)*NIN + nt*64;
  short* oe = outp + (size_t)e*NIN*KIN + (size_t)(nt*64)*KIN + kt*64;
  const int t = threadIdx.x;
  const int r = t >> 4, c = (t & 15) * 4;
#pragma unroll
  for (int p = 0; p < 4; ++p) {
    float4 v = *(const float4*)(ie + (size_t)(p*16 + r)*NIN + c);
    T[(p*16 + r)*66 + c + 0] = f2b(v.x);
    T[(p*16 + r)*66 + c + 1] = f2b(v.y);
    T[(p*16 + r)*66 + c + 2] = f2b(v.z);
    T[(p*16 + r)*66 + c + 3] = f2b(v.w);
  }
  __syncthreads();
#pragma unroll
  for (int p = 0; p < 4; ++p) {
    int rr = p*16 + r;
    short4v o = {T[(c+0)*66 + rr], T[(c+1)*66 + rr], T[(c+2)*66 + rr], T[(c+3)*66 + rr]};
    *(short4v*)(oe + (size_t)rr*KIN + c) = o;
  }
}

// ---------------- K1: xr(bf16) = mix; n(bf16) = rmsnorm ----------------
__global__ __launch_bounds__(256) void k_resid_rms(
    const float* __restrict__ x, const float* __restrict__ x0,
    const float* __restrict__ rmix, short* __restrict__ xr, short* __restrict__ nrm) {
  const int row = blockIdx.x;
  const int t = threadIdx.x;
  const int d = t * 4;
  const size_t base = (size_t)row * NDIM + d;
  float4 a  = *(const float4*)(x  + base);
  float4 b  = *(const float4*)(x0 + base);
  float4 m0 = *(const float4*)(rmix + d);
  float4 m1 = *(const float4*)(rmix + NDIM + d);
  float4 r;
  r.x = m0.x*a.x + m1.x*b.x;
  r.y = m0.y*a.y + m1.y*b.y;
  r.z = m0.z*a.z + m1.z*b.z;
  r.w = m0.w*a.w + m1.w*b.w;
  float ss = r.x*r.x + r.y*r.y + r.z*r.z + r.w*r.w;
  ss = wred64(ss);
  __shared__ float wsum[4];
  if ((t & 63) == 0) wsum[t >> 6] = ss;
  __syncthreads();
  float tot = wsum[0] + wsum[1] + wsum[2] + wsum[3];
  float rms = rsqrtf(tot * (1.0f/NDIM) + RMS_EPS);
  short4v xo = {f2b(r.x), f2b(r.y), f2b(r.z), f2b(r.w)};
  short4v no = {f2b(r.x*rms), f2b(r.y*rms), f2b(r.z*rms), f2b(r.w*rms)};
  *(short4v*)(xr + base) = xo;
  *(short4v*)(nrm + base) = no;
}

// ---------------- K2: MFMA GEMM 128x128, BK=32, global_load_lds staging ----------------
template <int MODE>
__global__ __launch_bounds__(256) void k_gemm_mfma(
    const short* __restrict__ A, int lda,
    const short* __restrict__ Bw, int K, int N,
    short* __restrict__ Cb, float* __restrict__ Cf, int ldc,
    const int* __restrict__ rowmap, const int* __restrict__ tiletab,
    const int* __restrict__ meta, const float* __restrict__ mscale) {
  __shared__ short sA[128*32];
  __shared__ short sB[128*32];
  int row0, end = 0x7fffffff, e = 0;
  if (MODE == 0) {
    row0 = blockIdx.y * 128;
  } else {
    e = tiletab[2*blockIdx.y];
    if (e < 0) return;
    row0 = tiletab[2*blockIdx.y + 1];
    end = meta[1 + e];
  }
  const int t = threadIdx.x;
  const int w = t >> 6, l = t & 63;
  const int wr = (w >> 1) * 64, wc = (w & 1) * 64;
  const int lrow = l & 15, lk8 = (l >> 4) * 8;
  const int srow0 = w*16 + (l >> 2);
  const int scol = (l & 3) * 8;
  const short* Bp = Bw + (size_t)e * N * K + (size_t)(blockIdx.x * 128) * K;
  const short* gA0;
  const short* gA1;
  if (MODE == 1) {
    int s0 = row0 + srow0;      if (s0 >= NTOK) s0 = NTOK - 1;
    int s1 = row0 + 64 + srow0; if (s1 >= NTOK) s1 = NTOK - 1;
    gA0 = A + (size_t)rowmap[s0] * lda + scol;
    gA1 = A + (size_t)rowmap[s1] * lda + scol;
  } else {
    gA0 = A + (size_t)(row0 + srow0) * lda + scol;
    gA1 = A + (size_t)(row0 + 64 + srow0) * lda + scol;
  }
  const short* gB0 = Bp + (size_t)srow0 * K + scol;
  const short* gB1 = Bp + (size_t)(64 + srow0) * K + scol;
  short* lA0 = sA + (w*16)*32;
  short* lA1 = sA + (64 + w*16)*32;
  short* lB0 = sB + (w*16)*32;
  short* lB1 = sB + (64 + w*16)*32;
  f32x4 acc[4][4];
#pragma unroll
  for (int m = 0; m < 4; ++m)
#pragma unroll
    for (int n = 0; n < 4; ++n) acc[m][n] = 0.f;
  for (int k0 = 0; k0 < K; k0 += 32) {
    __syncthreads();
    load_lds16(gA0, lA0);
    load_lds16(gA1, lA1);
    load_lds16(gB0, lB0);
    load_lds16(gB1, lB1);
    gA0 += 32; gA1 += 32; gB0 += 32; gB1 += 32;
    __syncthreads();
    bf16x8 af[4], bfr[4];
#pragma unroll
    for (int m = 0; m < 4; ++m)
      af[m] = *(const bf16x8*)&sA[(wr + m*16 + lrow)*32 + lk8];
#pragma unroll
    for (int n = 0; n < 4; ++n)
      bfr[n] = *(const bf16x8*)&sB[(wc + n*16 + lrow)*32 + lk8];
#pragma unroll
    for (int m = 0; m < 4; ++m)
#pragma unroll
      for (int n = 0; n < 4; ++n)
        acc[m][n] = __builtin_amdgcn_mfma_f32_16x16x32_bf16(af[m], bfr[n], acc[m][n], 0, 0, 0);
  }
  const int col0 = blockIdx.x * 128;
  if (MODE <= 1) {
#pragma unroll
    for (int m = 0; m < 4; ++m) {
#pragma unroll
      for (int r = 0; r < 4; ++r) {
        int rr = row0 + wr + m*16 + (l >> 4)*4 + r;
        if (rr < end) {
#pragma unroll
          for (int n = 0; n < 4; ++n)
            Cb[(size_t)rr * ldc + col0 + wc + n*16 + lrow] = f2b(acc[m][n][r]);
        }
      }
    }
  } else {
#pragma unroll
    for (int m = 0; m < 4; ++m) {
#pragma unroll
      for (int r = 0; r < 4; ++r) {
        int slot = row0 + wr + m*16 + (l >> 4)*4 + r;
        if (slot < end) {
          int tok = rowmap[slot];
#pragma unroll
          for (int n = 0; n < 4; ++n) {
            int cc = col0 + wc + n*16 + lrow;
            Cf[(size_t)tok * ldc + cc] += mscale[cc] * acc[m][n][r];
          }
        }
      }
    }
  }
}

// --------- K3: per-head rmsnorm + rope (QSCALE*q_gain folded into Q), bf16 in-place ---------
__global__ __launch_bounds__(256) void k_qk_norm_rope(
    short* __restrict__ qkv, const float* __restrict__ q_gain) {
  const int row = blockIdx.x;          // b*S+s
  const int t = threadIdx.x;
  const int w = t >> 6, lane = t & 63;
  const int s = row & (NSEQ - 1);
  const int fi = lane & 31;
  const float fr = (float)s * expf(-(float)fi * (LN_10000 / 32.0f));
  const float co = cosf(fr), si = sinf(fr);
#pragma unroll
  for (int h = w; h < NHEAD; h += 4) {
    short* p = qkv + (size_t)row*QKVN + h*HDIM + lane;
    float v = b2f(*p);
    float ssum = wred64(v*v);
    float rr = rsqrtf(ssum * (1.0f/HDIM) + RMS_EPS);
    float vn = v * rr;
    float partner = __shfl_xor(vn, 32);
    float o = (lane < 32) ? (vn*co + partner*si) : (vn*co - partner*si);
    *p = f2b(o * q_gain[h] * QSCALE);
  }
  if (w < NKVH) {
    short* p = qkv + (size_t)row*QKVN + 1024 + w*HDIM + lane;
    float v = b2f(*p);
    float ssum = wred64(v*v);
    float rr = rsqrtf(ssum * (1.0f/HDIM) + RMS_EPS);
    float vn = v * rr;
    float partner = __shfl_xor(vn, 32);
    float o = (lane < 32) ? (vn*co + partner*si) : (vn*co - partner*si);
    *p = f2b(o);
  }
}

// --------- K3b: V transpose to [b][kh][dim][seq] bf16 ---------
__global__ __launch_bounds__(256) void k_transpose_v(
    const short* __restrict__ qkv, short* __restrict__ vbT) {
  __shared__ short T[64*72];
  const int blk = blockIdx.x;
  const int st = blk & 31, kh = (blk >> 5) & 3, b = blk >> 7;
  const int t = threadIdx.x;
#pragma unroll
  for (int i = 0; i < 2; ++i) {
    int c = t + i*256;
    int s = c >> 3, d0 = (c & 7) * 8;
    bf16x8 v = *(const bf16x8*)(qkv + (size_t)(b*NSEQ + st*64 + s)*QKVN + 1280 + kh*HDIM + d0);
#pragma unroll
    for (int j = 0; j < 8; ++j) T[(d0 + j)*72 + s] = v[j];
  }
  __syncthreads();
#pragma unroll
  for (int i = 0; i < 2; ++i) {
    int c = t + i*256;
    int d = c >> 3, s0 = (c & 7) * 8;
    *(bf16x8*)(vbT + (size_t)((b*NKVH + kh)*HDIM + d)*NSEQ + st*64 + s0) = *(bf16x8*)&T[d*72 + s0];
  }
}

// ---------------- K4: causal flash attention, swapped-QK^T MFMA, 128-row Q tiles ----------------
// QK^T computed as mfma(K, Q): C col=lane&15 -> q-row, row -> k-pos.
// Each lane owns one q-row's 16 scores per 64-key tile: in-lane softmax + 2 shfls.
__global__ __launch_bounds__(256) void k_attn_mfma(
    const short* __restrict__ qkv, const short* __restrict__ vbT, short* __restrict__ y) {
  __shared__ short Ks[64*72];    // [key][dim]
  __shared__ short Vt[64*72];    // [dim][key]
  __shared__ short Ps[128*72];   // [qrow][key], per-wave-private rows
  const int t = threadIdx.x;
  const int l = t & 63, w = t >> 6;
  const int lrow = l & 15, g = l >> 4, lk8 = g * 8;
  const int bid = blockIdx.x;
  const int qt = bid & 15, h = (bid >> 4) & 15, b = bid >> 8;
  const int kh = h >> 2;
  bf16x8 qf[2][2];   // [qra][k-half]; Q as B-operand (col = q-row)
#pragma unroll
  for (int qra = 0; qra < 2; ++qra) {
    int qrow_g = b*NSEQ + qt*128 + qra*64 + w*16 + lrow;
#pragma unroll
    for (int hf = 0; hf < 2; ++hf)
      qf[qra][hf] = *(const bf16x8*)(qkv + (size_t)qrow_g*QKVN + h*HDIM + hf*32 + lk8);
  }
  float m_i[2] = {-INFINITY, -INFINITY};
  float l_i[2] = {0.f, 0.f};
  f32x4 O[2][4];
#pragma unroll
  for (int qra = 0; qra < 2; ++qra)
#pragma unroll
    for (int db = 0; db < 4; ++db) O[qra][db] = 0.f;
  const int ktmax = 2*qt + 1;
  for (int kt = 0; kt <= ktmax; ++kt) {
    __syncthreads();
#pragma unroll
    for (int i = 0; i < 2; ++i) {
      int c = t + i*256;
      int r0 = c >> 3, d0 = (c & 7) * 8;
      *(bf16x8*)&Ks[r0*72 + d0] =
          *(const bf16x8*)(qkv + (size_t)(b*NSEQ + kt*64 + r0)*QKVN + 1024 + kh*HDIM + d0);
      *(bf16x8*)&Vt[r0*72 + d0] =
          *(const bf16x8*)(vbT + (size_t)((b*NKVH + kh)*HDIM + r0)*NSEQ + kt*64 + d0);
    }
    __syncthreads();
    const int qra0 = (kt == ktmax) ? 1 : 0;   // q-rows 0..63 fully masked on last tile
    bf16x8 pf[2][2];
#pragma unroll
    for (int qra = 0; qra < 2; ++qra) {
      if (qra >= qra0) {
        f32x4 sc[4];
#pragma unroll
        for (int nb = 0; nb < 4; ++nb) sc[nb] = 0.f;
#pragma unroll
        for (int nb = 0; nb < 4; ++nb) {
          bf16x8 kf0 = *(const bf16x8*)&Ks[(nb*16 + lrow)*72 + lk8];
          bf16x8 kf1 = *(const bf16x8*)&Ks[(nb*16 + lrow)*72 + 32 + lk8];
          sc[nb] = __builtin_amdgcn_mfma_f32_16x16x32_bf16(kf0, qf[qra][0], sc[nb], 0, 0, 0);
          sc[nb] = __builtin_amdgcn_mfma_f32_16x16x32_bf16(kf1, qf[qra][1], sc[nb], 0, 0, 0);
        }
        if (kt >= 2*qt) {   // diagonal tiles: elementwise causal mask
          int qg = qt*128 + qra*64 + w*16 + lrow;
#pragma unroll
          for (int nb = 0; nb < 4; ++nb)
#pragma unroll
            for (int r = 0; r < 4; ++r)
              if (kt*64 + nb*16 + g*4 + r > qg) sc[nb][r] = -INFINITY;
        }
        // in-lane softmax over 16 scores (log2 domain) + cross-replica reduce
        float rm = sc[0][0];
#pragma unroll
        for (int nb = 0; nb < 4; ++nb)
#pragma unroll
          for (int r = 0; r < 4; ++r) rm = fmaxf(rm, sc[nb][r]);
        rm = fmaxf(rm, __shfl_xor(rm, 16));
        rm = fmaxf(rm, __shfl_xor(rm, 32));
        float mn = fmaxf(m_i[qra], rm);
        float fac = ex2(m_i[qra] - mn);
        float rs = 0.f;
#pragma unroll
        for (int nb = 0; nb < 4; ++nb) {
#pragma unroll
          for (int r = 0; r < 4; ++r) {
            float p = ex2(sc[nb][r] - mn);
            sc[nb][r] = p;
            rs += p;
          }
        }
        rs += __shfl_xor(rs, 16);
        rs += __shfl_xor(rs, 32);
        l_i[qra] = l_i[qra]*fac + rs;
        m_i[qra] = mn;
        // P -> LDS: 4x ds_write_b64, own-wave rows only
        short* prow = &Ps[(qra*64 + w*16 + lrow)*72];
#pragma unroll
        for (int nb = 0; nb < 4; ++nb) {
          short4v pk = {f2b(sc[nb][0]), f2b(sc[nb][1]), f2b(sc[nb][2]), f2b(sc[nb][3])};
          *(short4v*)(prow + nb*16 + g*4) = pk;
        }
        // O rescale: fac lives at lane (q-row); fetch per output reg
#pragma unroll
        for (int r = 0; r < 4; ++r) {
          float ff = __shfl(fac, g*4 + r);
#pragma unroll
          for (int db = 0; db < 4; ++db) O[qra][db][r] *= ff;
        }
        pf[qra][0] = *(const bf16x8*)&Ps[(qra*64 + w*16 + lrow)*72 + lk8];
        pf[qra][1] = *(const bf16x8*)&Ps[(qra*64 + w*16 + lrow)*72 + 32 + lk8];
      }
    }
#pragma unroll
    for (int db = 0; db < 4; ++db) {
      bf16x8 vf0 = *(const bf16x8*)&Vt[(db*16 + lrow)*72 + lk8];
      bf16x8 vf1 = *(const bf16x8*)&Vt[(db*16 + lrow)*72 + 32 + lk8];
      if (qra0 == 0) {
        O[0][db] = __builtin_amdgcn_mfma_f32_16x16x32_bf16(pf[0][0], vf0, O[0][db], 0, 0, 0);
        O[0][db] = __builtin_amdgcn_mfma_f32_16x16x32_bf16(pf[0][1], vf1, O[0][db], 0, 0, 0);
      }
      O[1][db] = __builtin_amdgcn_mfma_f32_16x16x32_bf16(pf[1][0], vf0, O[1][db], 0, 0, 0);
      O[1][db] = __builtin_amdgcn_mfma_f32_16x16x32_bf16(pf[1][1], vf1, O[1][db], 0, 0, 0);
    }
  }
#pragma unroll
  for (int qra = 0; qra < 2; ++qra) {
    float linv = 1.0f / l_i[qra];
#pragma unroll
    for (int r = 0; r < 4; ++r) {
      float inv = __shfl(linv, g*4 + r);
      int rowo = b*NSEQ + qt*128 + qra*64 + w*16 + g*4 + r;
#pragma unroll
      for (int db = 0; db < 4; ++db)
        y[(size_t)rowo*NDIM + h*HDIM + db*16 + lrow] = f2b(O[qra][db][r] * inv);
    }
  }
}

// --------- K5: x2/v_next -> out(f32) ; mbuf = rmsnorm(x2) bf16 ---------
__global__ __launch_bounds__(256) void k_fuse_vel(
    const short* __restrict__ xr, const short* __restrict__ aout,
    const float* __restrict__ vel, const float* __restrict__ ascale,
    const float* __restrict__ mu, float* __restrict__ out, short* __restrict__ mbuf) {
  const int row = blockIdx.x;
  const int t = threadIdx.x;
  const int d = t * 4;
  const size_t base = (size_t)row * NDIM + d;
  short4v a4 = *(const short4v*)(xr + base);
  short4v o4 = *(const short4v*)(aout + base);
  float4 vv = *(const float4*)(vel + base);
  float4 as = *(const float4*)(ascale + d);
  float4 mu4 = *(const float4*)(mu + d);
  float xs[4], vns[4];
  const float asl[4] = {as.x, as.y, as.z, as.w};
  const float mul[4] = {mu4.x, mu4.y, mu4.z, mu4.w};
  const float vvl[4] = {vv.x, vv.y, vv.z, vv.w};
#pragma unroll
  for (int i = 0; i < 4; ++i) {
    float x1 = b2f(a4[i]) + asl[i] * b2f(o4[i]);
    float muc = fminf(fmaxf(mul[i], 0.5f), 1.5f);
    float vn = fminf(fmaxf(0.95f*vvl[i] - 0.3f*(x1 - muc), -3.f), 3.f);
    xs[i] = x1 + 0.01f*vn;
    vns[i] = vn;
  }
  float4 x2 = {xs[0], xs[1], xs[2], xs[3]};
  float4 vnq = {vns[0], vns[1], vns[2], vns[3]};
  *(float4*)(out + base) = x2;
  *(float4*)(out + (size_t)NTOK*NDIM + base) = vnq;
  float ss = xs[0]*xs[0] + xs[1]*xs[1] + xs[2]*xs[2] + xs[3]*xs[3];
  ss = wred64(ss);
  __shared__ float wsum[4];
  if ((t & 63) == 0) wsum[t >> 6] = ss;
  __syncthreads();
  float tot = wsum[0] + wsum[1] + wsum[2] + wsum[3];
  float rms = rsqrtf(tot * (1.0f/NDIM) + RMS_EPS);
  short4v m4 = {f2b(xs[0]*rms), f2b(xs[1]*rms), f2b(xs[2]*rms), f2b(xs[3]*rms)};
  *(short4v*)(mbuf + base) = m4;
}

// --------- K6a: token routing (128-row tiles) ---------
__global__ __launch_bounds__(256) void k_route(
    const int* __restrict__ eids, int* __restrict__ rowmap,
    int* __restrict__ tiletab, int* __restrict__ meta) {
  __shared__ int cnt[NEXP];
  __shared__ int ctr[NEXP];
  const int t = threadIdx.x;
  if (t < NEXP) cnt[t] = 0;
  __syncthreads();
  for (int i = t; i < NTOK; i += 256) atomicAdd(&cnt[eids[i]], 1);
  __syncthreads();
  if (t == 0) {
    int off = 0, tile = 0;
    for (int e = 0; e < NEXP; ++e) {
      ctr[e] = off;
      int nt_e = (cnt[e] + 127) >> 7;
      for (int j = 0; j < nt_e; ++j) { tiletab[2*tile] = e; tiletab[2*tile+1] = off + j*128; ++tile; }
      off += cnt[e];
      meta[1 + e] = off;
    }
    meta[0] = tile;
    for (int j = tile; j < MAXTILE; ++j) { tiletab[2*j] = -1; tiletab[2*j+1] = 0; }
  }
  __syncthreads();
  for (int i = t; i < NTOK; i += 256) {
    int e = eids[i];
    int slot = atomicAdd(&ctr[e], 1);
    rowmap[slot] = i;
  }
}

// --------- K6b: h = silu(g)*u from gu rows ---------
__global__ __launch_bounds__(256) void k_silu(
    const short* __restrict__ gu, short* __restrict__ hb) {
  int gid = blockIdx.x * 256 + threadIdx.x;
  int row = gid >> 7, c4 = (gid & 127) * 4;
  short4v g = *(const short4v*)(gu + (size_t)row*1024 + c4);
  short4v u = *(const short4v*)(gu + (size_t)row*1024 + 512 + c4);
  short4v o;
#pragma unroll
  for (int i = 0; i < 4; ++i) {
    float gf = b2f(g[i]), uf = b2f(u[i]);
    o[i] = f2b(gf / (1.0f + __expf(-gf)) * uf);
  }
  *(short4v*)(hb + (size_t)row*512 + c4) = o;
}

extern "C" void kernel_launch(void* const* d_in, const int* in_sizes, int n_in,
                              void* d_out, int out_size, void* d_ws, size_t ws_size,
                              hipStream_t stream) {
  const float* x      = (const float*)d_in[0];
  const float* x0     = (const float*)d_in[1];
  const float* vel    = (const float*)d_in[2];
  const float* rmix   = (const float*)d_in[3];
  const float* ascale = (const float*)d_in[4];
  const float* mscale = (const float*)d_in[5];
  const float* cq_w   = (const float*)d_in[6];
  const float* ck_w   = (const float*)d_in[7];
  const float* cv_w   = (const float*)d_in[8];
  const float* proj_w = (const float*)d_in[9];
  const float* q_gain = (const float*)d_in[10];
  const float* mu     = (const float*)d_in[11];
  const float* gate_up= (const float*)d_in[12];
  const float* down   = (const float*)d_in[13];
  const int*   eids   = (const int*)d_in[14];
  float* out = (float*)d_out;
  char* base = (char*)d_ws;

  const size_t MB = 1024*1024;
  short* wqkv  = (short*)base;
  short* wproj = (short*)(base + 3*MB);
  int*   rowmap  = (int*)(base + 5*MB);
  int*   tiletab = rowmap + NTOK;
  int*   meta    = tiletab + 2*MAXTILE;
  short* wgu_t = (short*)(base + 6*MB);
  short* hbuf  = wgu_t;
  short* xr    = (short*)(base + 22*MB);
  short* gu    = xr;
  short* nbuf  = (short*)(base + 30*MB);
  short* ybuf  = nbuf;
  short* mbuf  = nbuf;
  short* wdn_t = nbuf;
  short* qkv   = (short*)(base + 38*MB);
  short* aout  = qkv;
  short* vbT   = (short*)(base + 50*MB);

  k_w_cast<<<2560, 256, 0, stream>>>(cq_w, ck_w, cv_w, proj_w, wqkv, wproj);
  k_w_transpose<<<dim3(16, 16, 8), 256, 0, stream>>>(gate_up, wgu_t, 1024, 1024);
  k_resid_rms<<<NTOK, 256, 0, stream>>>(x, x0, rmix, xr, nbuf);
  k_gemm_mfma<0><<<dim3(QKVN/128, NTOK/128), 256, 0, stream>>>(
      nbuf, NDIM, wqkv, NDIM, QKVN, qkv, nullptr, QKVN, nullptr, nullptr, nullptr, nullptr);
  k_qk_norm_rope<<<NTOK, 256, 0, stream>>>(qkv, q_gain);
  k_transpose_v<<<NBATCH*NKVH*(NSEQ/64), 256, 0, stream>>>(qkv, vbT);
  k_attn_mfma<<<NBATCH*NHEAD*(NSEQ/128), 256, 0, stream>>>(qkv, vbT, ybuf);
  k_gemm_mfma<0><<<dim3(NDIM/128, NTOK/128), 256, 0, stream>>>(
      ybuf, NDIM, wproj, NDIM, NDIM, aout, nullptr, NDIM, nullptr, nullptr, nullptr, nullptr);
  k_fuse_vel<<<NTOK, 256, 0, stream>>>(xr, aout, vel, ascale, mu, out, mbuf);
  k_route<<<1, 256, 0, stream>>>(eids, rowmap, tiletab, meta);
  k_gemm_mfma<1><<<dim3(1024/128, MAXTILE), 256, 0, stream>>>(
      mbuf, NDIM, wgu_t, NDIM, 1024, gu, nullptr, 1024, rowmap, tiletab, meta, nullptr);
  k_w_transpose<<<dim3(8, 16, 8), 256, 0, stream>>>(down, wdn_t, 512, 1024);
  k_silu<<<(NTOK*512)/(4*256), 256, 0, stream>>>(gu, hbuf);
  k_gemm_mfma<2><<<dim3(NDIM/128, MAXTILE), 256, 0, stream>>>(
      hbuf, NINTER, wdn_t, NINTER, NDIM, nullptr, out, NDIM, rowmap, tiletab, meta, mscale);
}

// Round 7
// 235.975 us; speedup vs baseline: 15.2911x; 1.1126x over previous
//
#include <hip/hip_runtime.h>
#include <hip/hip_bf16.h>
#include <math.h>

#define NBATCH 2
#define NSEQ   2048
#define NDIM   1024
#define NHEAD  16
#define NKVH   4
#define HDIM   64
#define KVD    256
#define NEXP   8
#define NINTER 512
#define NTOK   (NBATCH*NSEQ)
#define QKVN   1536
#define MAXTILE 40
#define RMS_EPS 1.1920929e-07f
#define LN_10000 9.210340371976184f
#define QSCALE (0.125f * 1.44269504088896f)   // 1/sqrt(64) * log2(e), folded into Q
#define DEFER_THR 11.5f                        // log2 domain ~= e^8

typedef __attribute__((ext_vector_type(8))) short bf16x8;
typedef __attribute__((ext_vector_type(4))) short short4v;
typedef __attribute__((ext_vector_type(4))) float f32x4;

__device__ __forceinline__ short f2b(float f) {
  unsigned u = __builtin_bit_cast(unsigned, f);
  unsigned r = (u + 0x7fffu + ((u >> 16) & 1u)) >> 16;  // RNE
  return (short)r;
}
__device__ __forceinline__ float b2f(short s) {
  unsigned u = ((unsigned)(unsigned short)s) << 16;
  return __builtin_bit_cast(float, u);
}
__device__ __forceinline__ float ex2(float x) {   // 2^x via v_exp_f32
  float r; asm("v_exp_f32 %0, %1" : "=v"(r) : "v"(x)); return r;
}
__device__ __forceinline__ void load_lds16(const short* g, short* l) {
  __builtin_amdgcn_global_load_lds((const __attribute__((address_space(1))) void*)g,
                                   (__attribute__((address_space(3))) void*)l, 16, 0, 0);
}

__device__ __forceinline__ float wred64(float v) {
#pragma unroll
  for (int m = 32; m >= 1; m >>= 1) v += __shfl_xor(v, m);
  return v;
}

// ---------------- W0: cast attention weights to bf16 (wqkv concat + wproj) ----------------
__global__ __launch_bounds__(256) void k_w_cast(
    const float* __restrict__ cq, const float* __restrict__ ck,
    const float* __restrict__ cv, const float* __restrict__ pw,
    short* __restrict__ wqkv, short* __restrict__ wproj) {
  const int row = blockIdx.x;
  const int c = threadIdx.x * 4;
  const float* src; short* dst;
  if (row < 1024)      { src = cq + (size_t)row*NDIM;        dst = wqkv + (size_t)row*NDIM; }
  else if (row < 1280) { src = ck + (size_t)(row-1024)*NDIM; dst = wqkv + (size_t)row*NDIM; }
  else if (row < 1536) { src = cv + (size_t)(row-1280)*NDIM; dst = wqkv + (size_t)row*NDIM; }
  else                 { src = pw + (size_t)(row-1536)*NDIM; dst = wproj + (size_t)(row-1536)*NDIM; }
  float4 v = *(const float4*)(src + c);
  short4v o = {f2b(v.x), f2b(v.y), f2b(v.z), f2b(v.w)};
  *(short4v*)(dst + c) = o;
}

// ---------------- W1: per-expert transpose fp32 [KIN][NIN] -> bf16 [NIN][KIN] ----------------
__global__ __launch_bounds__(256) void k_w_transpose(
    const float* __restrict__ in, short* __restrict__ outp, int KIN, int NIN) {
  __shared__ short T[64*66];
  const int kt = blockIdx.x, nt = blockIdx.y, e = blockIdx.z;
  const float* ie = in + (size_t)e*KIN*NIN + (size_t)(kt*64)*NIN + nt*64;
  short* oe = outp + (size_t)e*NIN*KIN + (size_t)(nt*64)*KIN + kt*64;
  const int t = threadIdx.x;
  const int r = t >> 4, c = (t & 15) * 4;
#pragma unroll
  for (int p = 0; p < 4; ++p) {
    float4 v = *(const float4*)(ie + (size_t)(p*16 + r)*NIN + c);
    T[(p*16 + r)*66 + c + 0] = f2b(v.x);
    T[(p*16 + r)*66 + c + 1] = f2b(v.y);
    T[(p*16 + r)*66 + c + 2] = f2b(v.z);
    T[(p*16 + r)*66 + c + 3] = f2b(v.w);
  }
  __syncthreads();
#pragma unroll
  for (int p = 0; p < 4; ++p) {
    int rr = p*16 + r;
    short4v o = {T[(c+0)*66 + rr], T[(c+1)*66 + rr], T[(c+2)*66 + rr], T[(c+3)*66 + rr]};
    *(short4v*)(oe + (size_t)rr*KIN + c) = o;
  }
}

// ---------------- K1: xr(bf16) = mix; n(bf16) = rmsnorm ----------------
__global__ __launch_bounds__(256) void k_resid_rms(
    const float* __restrict__ x, const float* __restrict__ x0,
    const float* __restrict__ rmix, short* __restrict__ xr, short* __restrict__ nrm) {
  const int row = blockIdx.x;
  const int t = threadIdx.x;
  const int d = t * 4;
  const size_t base = (size_t)row * NDIM + d;
  float4 a  = *(const float4*)(x  + base);
  float4 b  = *(const float4*)(x0 + base);
  float4 m0 = *(const float4*)(rmix + d);
  float4 m1 = *(const float4*)(rmix + NDIM + d);
  float4 r;
  r.x = m0.x*a.x + m1.x*b.x;
  r.y = m0.y*a.y + m1.y*b.y;
  r.z = m0.z*a.z + m1.z*b.z;
  r.w = m0.w*a.w + m1.w*b.w;
  float ss = r.x*r.x + r.y*r.y + r.z*r.z + r.w*r.w;
  ss = wred64(ss);
  __shared__ float wsum[4];
  if ((t & 63) == 0) wsum[t >> 6] = ss;
  __syncthreads();
  float tot = wsum[0] + wsum[1] + wsum[2] + wsum[3];
  float rms = rsqrtf(tot * (1.0f/NDIM) + RMS_EPS);
  short4v xo = {f2b(r.x), f2b(r.y), f2b(r.z), f2b(r.w)};
  short4v no = {f2b(r.x*rms), f2b(r.y*rms), f2b(r.z*rms), f2b(r.w*rms)};
  *(short4v*)(xr + base) = xo;
  *(short4v*)(nrm + base) = no;
}

// ---------------- K2: MFMA GEMM 128x128, BK=32, global_load_lds staging ----------------
template <int MODE>
__global__ __launch_bounds__(256) void k_gemm_mfma(
    const short* __restrict__ A, int lda,
    const short* __restrict__ Bw, int K, int N,
    short* __restrict__ Cb, float* __restrict__ Cf, int ldc,
    const int* __restrict__ rowmap, const int* __restrict__ tiletab,
    const int* __restrict__ meta, const float* __restrict__ mscale) {
  __shared__ short sA[128*32];
  __shared__ short sB[128*32];
  int row0, end = 0x7fffffff, e = 0;
  if (MODE == 0) {
    row0 = blockIdx.y * 128;
  } else {
    e = tiletab[2*blockIdx.y];
    if (e < 0) return;
    row0 = tiletab[2*blockIdx.y + 1];
    end = meta[1 + e];
  }
  const int t = threadIdx.x;
  const int w = t >> 6, l = t & 63;
  const int wr = (w >> 1) * 64, wc = (w & 1) * 64;
  const int lrow = l & 15, lk8 = (l >> 4) * 8;
  const int srow0 = w*16 + (l >> 2);
  const int scol = (l & 3) * 8;
  const short* Bp = Bw + (size_t)e * N * K + (size_t)(blockIdx.x * 128) * K;
  const short* gA0;
  const short* gA1;
  if (MODE == 1) {
    int s0 = row0 + srow0;      if (s0 >= NTOK) s0 = NTOK - 1;
    int s1 = row0 + 64 + srow0; if (s1 >= NTOK) s1 = NTOK - 1;
    gA0 = A + (size_t)rowmap[s0] * lda + scol;
    gA1 = A + (size_t)rowmap[s1] * lda + scol;
  } else {
    gA0 = A + (size_t)(row0 + srow0) * lda + scol;
    gA1 = A + (size_t)(row0 + 64 + srow0) * lda + scol;
  }
  const short* gB0 = Bp + (size_t)srow0 * K + scol;
  const short* gB1 = Bp + (size_t)(64 + srow0) * K + scol;
  short* lA0 = sA + (w*16)*32;
  short* lA1 = sA + (64 + w*16)*32;
  short* lB0 = sB + (w*16)*32;
  short* lB1 = sB + (64 + w*16)*32;
  f32x4 acc[4][4];
#pragma unroll
  for (int m = 0; m < 4; ++m)
#pragma unroll
    for (int n = 0; n < 4; ++n) acc[m][n] = 0.f;
  for (int k0 = 0; k0 < K; k0 += 32) {
    __syncthreads();
    load_lds16(gA0, lA0);
    load_lds16(gA1, lA1);
    load_lds16(gB0, lB0);
    load_lds16(gB1, lB1);
    gA0 += 32; gA1 += 32; gB0 += 32; gB1 += 32;
    __syncthreads();
    bf16x8 af[4], bfr[4];
#pragma unroll
    for (int m = 0; m < 4; ++m)
      af[m] = *(const bf16x8*)&sA[(wr + m*16 + lrow)*32 + lk8];
#pragma unroll
    for (int n = 0; n < 4; ++n)
      bfr[n] = *(const bf16x8*)&sB[(wc + n*16 + lrow)*32 + lk8];
#pragma unroll
    for (int m = 0; m < 4; ++m)
#pragma unroll
      for (int n = 0; n < 4; ++n)
        acc[m][n] = __builtin_amdgcn_mfma_f32_16x16x32_bf16(af[m], bfr[n], acc[m][n], 0, 0, 0);
  }
  const int col0 = blockIdx.x * 128;
  if (MODE <= 1) {
#pragma unroll
    for (int m = 0; m < 4; ++m) {
#pragma unroll
      for (int r = 0; r < 4; ++r) {
        int rr = row0 + wr + m*16 + (l >> 4)*4 + r;
        if (rr < end) {
#pragma unroll
          for (int n = 0; n < 4; ++n)
            Cb[(size_t)rr * ldc + col0 + wc + n*16 + lrow] = f2b(acc[m][n][r]);
        }
      }
    }
  } else {
#pragma unroll
    for (int m = 0; m < 4; ++m) {
#pragma unroll
      for (int r = 0; r < 4; ++r) {
        int slot = row0 + wr + m*16 + (l >> 4)*4 + r;
        if (slot < end) {
          int tok = rowmap[slot];
#pragma unroll
          for (int n = 0; n < 4; ++n) {
            int cc = col0 + wc + n*16 + lrow;
            Cf[(size_t)tok * ldc + cc] += mscale[cc] * acc[m][n][r];
          }
        }
      }
    }
  }
}

// --------- K3: per-head rmsnorm + rope (QSCALE*q_gain folded into Q), bf16 in-place ---------
__global__ __launch_bounds__(256) void k_qk_norm_rope(
    short* __restrict__ qkv, const float* __restrict__ q_gain) {
  const int row = blockIdx.x;          // b*S+s
  const int t = threadIdx.x;
  const int w = t >> 6, lane = t & 63;
  const int s = row & (NSEQ - 1);
  const int fi = lane & 31;
  const float fr = (float)s * expf(-(float)fi * (LN_10000 / 32.0f));
  const float co = cosf(fr), si = sinf(fr);
#pragma unroll
  for (int h = w; h < NHEAD; h += 4) {
    short* p = qkv + (size_t)row*QKVN + h*HDIM + lane;
    float v = b2f(*p);
    float ssum = wred64(v*v);
    float rr = rsqrtf(ssum * (1.0f/HDIM) + RMS_EPS);
    float vn = v * rr;
    float partner = __shfl_xor(vn, 32);
    float o = (lane < 32) ? (vn*co + partner*si) : (vn*co - partner*si);
    *p = f2b(o * q_gain[h] * QSCALE);
  }
  if (w < NKVH) {
    short* p = qkv + (size_t)row*QKVN + 1024 + w*HDIM + lane;
    float v = b2f(*p);
    float ssum = wred64(v*v);
    float rr = rsqrtf(ssum * (1.0f/HDIM) + RMS_EPS);
    float vn = v * rr;
    float partner = __shfl_xor(vn, 32);
    float o = (lane < 32) ? (vn*co + partner*si) : (vn*co - partner*si);
    *p = f2b(o);
  }
}

// --------- K3b: V transpose to [b][kh][dim][seq] bf16 ---------
__global__ __launch_bounds__(256) void k_transpose_v(
    const short* __restrict__ qkv, short* __restrict__ vbT) {
  __shared__ short T[64*72];
  const int blk = blockIdx.x;
  const int st = blk & 31, kh = (blk >> 5) & 3, b = blk >> 7;
  const int t = threadIdx.x;
#pragma unroll
  for (int i = 0; i < 2; ++i) {
    int c = t + i*256;
    int s = c >> 3, d0 = (c & 7) * 8;
    bf16x8 v = *(const bf16x8*)(qkv + (size_t)(b*NSEQ + st*64 + s)*QKVN + 1280 + kh*HDIM + d0);
#pragma unroll
    for (int j = 0; j < 8; ++j) T[(d0 + j)*72 + s] = v[j];
  }
  __syncthreads();
#pragma unroll
  for (int i = 0; i < 2; ++i) {
    int c = t + i*256;
    int d = c >> 3, s0 = (c & 7) * 8;
    *(bf16x8*)(vbT + (size_t)((b*NKVH + kh)*HDIM + d)*NSEQ + st*64 + s0) = *(bf16x8*)&T[d*72 + s0];
  }
}

// ---------------- K4: causal flash attention, swapped-QK^T MFMA, 128-row Q tiles ----------------
// v2: double-buffered K/V with async reg-staging (loads for kt+1 issued before compute of kt),
//     one barrier per tile, defer-max (log2-domain THR), qt balance remap for b=1.
__global__ __launch_bounds__(256) void k_attn_mfma(
    const short* __restrict__ qkv, const short* __restrict__ vbT, short* __restrict__ y) {
  __shared__ short Ks[2][64*72];   // [key][dim]
  __shared__ short Vt[2][64*72];   // [dim][key]
  __shared__ short Ps[128*72];     // [qrow][key], per-wave-private rows
  const int t = threadIdx.x;
  const int l = t & 63, w = t >> 6;
  const int lrow = l & 15, g = l >> 4, lk8 = g * 8;
  const int bid = blockIdx.x;
  int qt = bid & 15;
  const int h = (bid >> 4) & 15, b = bid >> 8;
  if (b & 1) qt = 15 - qt;   // balance: co-resident pairs (bid, bid+256) sum to 34 tiles
  const int kh = h >> 2;
  bf16x8 qf[2][2];   // [qra][k-half]; Q as B-operand (col = q-row)
#pragma unroll
  for (int qra = 0; qra < 2; ++qra) {
    int qrow_g = b*NSEQ + qt*128 + qra*64 + w*16 + lrow;
#pragma unroll
    for (int hf = 0; hf < 2; ++hf)
      qf[qra][hf] = *(const bf16x8*)(qkv + (size_t)qrow_g*QKVN + h*HDIM + hf*32 + lk8);
  }
  // staging: thread covers K/V tile chunks (row r0a, r0a+32) x 16B col d0a
  const int r0a = t >> 3;
  const int d0a = (t & 7) * 8;
  const short* kgbase = qkv + 1024 + (size_t)kh*HDIM;
  const short* vgbase = vbT + (size_t)((b*NKVH + kh)*HDIM)*NSEQ;
  bf16x8 kr0, kr1, vr0, vr1;
#define LOADKV(KT) do { \
    kr0 = *(const bf16x8*)(kgbase + (size_t)(b*NSEQ + (KT)*64 + r0a)*QKVN + d0a); \
    kr1 = *(const bf16x8*)(kgbase + (size_t)(b*NSEQ + (KT)*64 + r0a + 32)*QKVN + d0a); \
    vr0 = *(const bf16x8*)(vgbase + (size_t)r0a*NSEQ + (KT)*64 + d0a); \
    vr1 = *(const bf16x8*)(vgbase + (size_t)(r0a + 32)*NSEQ + (KT)*64 + d0a); \
  } while (0)
  float m_i[2] = {-INFINITY, -INFINITY};
  float l_i[2] = {0.f, 0.f};
  f32x4 O[2][4];
#pragma unroll
  for (int qra = 0; qra < 2; ++qra)
#pragma unroll
    for (int db = 0; db < 4; ++db) O[qra][db] = 0.f;
  const int ktmax = 2*qt + 1;
  LOADKV(0);
  for (int kt = 0; kt <= ktmax; ++kt) {
    const int buf = kt & 1;
    // write staged regs -> LDS (vmcnt wait auto-inserted), then ONE barrier
    *(bf16x8*)&Ks[buf][r0a*72 + d0a] = kr0;
    *(bf16x8*)&Ks[buf][(r0a + 32)*72 + d0a] = kr1;
    *(bf16x8*)&Vt[buf][r0a*72 + d0a] = vr0;
    *(bf16x8*)&Vt[buf][(r0a + 32)*72 + d0a] = vr1;
    __syncthreads();
    if (kt < ktmax) LOADKV(kt + 1);   // async prefetch: lands during compute below
    const int qra0 = (kt == ktmax) ? 1 : 0;   // q-rows 0..63 fully masked on last tile
    bf16x8 pf[2][2];
#pragma unroll
    for (int qra = 0; qra < 2; ++qra) {
      if (qra >= qra0) {
        f32x4 sc[4];
#pragma unroll
        for (int nb = 0; nb < 4; ++nb) sc[nb] = 0.f;
#pragma unroll
        for (int nb = 0; nb < 4; ++nb) {
          bf16x8 kf0 = *(const bf16x8*)&Ks[buf][(nb*16 + lrow)*72 + lk8];
          bf16x8 kf1 = *(const bf16x8*)&Ks[buf][(nb*16 + lrow)*72 + 32 + lk8];
          sc[nb] = __builtin_amdgcn_mfma_f32_16x16x32_bf16(kf0, qf[qra][0], sc[nb], 0, 0, 0);
          sc[nb] = __builtin_amdgcn_mfma_f32_16x16x32_bf16(kf1, qf[qra][1], sc[nb], 0, 0, 0);
        }
        if (kt >= 2*qt) {   // diagonal tiles: elementwise causal mask
          int qg = qt*128 + qra*64 + w*16 + lrow;
#pragma unroll
          for (int nb = 0; nb < 4; ++nb)
#pragma unroll
            for (int r = 0; r < 4; ++r)
              if (kt*64 + nb*16 + g*4 + r > qg) sc[nb][r] = -INFINITY;
        }
        // in-lane max over 16 scores + cross-replica reduce
        float rm = sc[0][0];
#pragma unroll
        for (int nb = 0; nb < 4; ++nb)
#pragma unroll
          for (int r = 0; r < 4; ++r) rm = fmaxf(rm, sc[nb][r]);
        rm = fmaxf(rm, __shfl_xor(rm, 16));
        rm = fmaxf(rm, __shfl_xor(rm, 32));
        // defer-max: only rescale when the running max grew materially
        if (!__all(rm <= m_i[qra] + DEFER_THR)) {
          float mn = fmaxf(m_i[qra], rm);
          float fac = ex2(m_i[qra] - mn);
          l_i[qra] *= fac;
          m_i[qra] = mn;
#pragma unroll
          for (int r = 0; r < 4; ++r) {
            float ff = __shfl(fac, g*4 + r);
#pragma unroll
            for (int db = 0; db < 4; ++db) O[qra][db][r] *= ff;
          }
        }
        float rs = 0.f;
#pragma unroll
        for (int nb = 0; nb < 4; ++nb) {
#pragma unroll
          for (int r = 0; r < 4; ++r) {
            float p = ex2(sc[nb][r] - m_i[qra]);
            sc[nb][r] = p;
            rs += p;
          }
        }
        rs += __shfl_xor(rs, 16);
        rs += __shfl_xor(rs, 32);
        l_i[qra] += rs;
        // P -> LDS: 4x ds_write_b64, own-wave rows only (no barrier needed)
        short* prow = &Ps[(qra*64 + w*16 + lrow)*72];
#pragma unroll
        for (int nb = 0; nb < 4; ++nb) {
          short4v pk = {f2b(sc[nb][0]), f2b(sc[nb][1]), f2b(sc[nb][2]), f2b(sc[nb][3])};
          *(short4v*)(prow + nb*16 + g*4) = pk;
        }
        pf[qra][0] = *(const bf16x8*)&Ps[(qra*64 + w*16 + lrow)*72 + lk8];
        pf[qra][1] = *(const bf16x8*)&Ps[(qra*64 + w*16 + lrow)*72 + 32 + lk8];
      }
    }
#pragma unroll
    for (int db = 0; db < 4; ++db) {
      bf16x8 vf0 = *(const bf16x8*)&Vt[buf][(db*16 + lrow)*72 + lk8];
      bf16x8 vf1 = *(const bf16x8*)&Vt[buf][(db*16 + lrow)*72 + 32 + lk8];
      if (qra0 == 0) {
        O[0][db] = __builtin_amdgcn_mfma_f32_16x16x32_bf16(pf[0][0], vf0, O[0][db], 0, 0, 0);
        O[0][db] = __builtin_amdgcn_mfma_f32_16x16x32_bf16(pf[0][1], vf1, O[0][db], 0, 0, 0);
      }
      O[1][db] = __builtin_amdgcn_mfma_f32_16x16x32_bf16(pf[1][0], vf0, O[1][db], 0, 0, 0);
      O[1][db] = __builtin_amdgcn_mfma_f32_16x16x32_bf16(pf[1][1], vf1, O[1][db], 0, 0, 0);
    }
  }
#undef LOADKV
#pragma unroll
  for (int qra = 0; qra < 2; ++qra) {
    float linv = 1.0f / l_i[qra];
#pragma unroll
    for (int r = 0; r < 4; ++r) {
      float inv = __shfl(linv, g*4 + r);
      int rowo = b*NSEQ + qt*128 + qra*64 + w*16 + g*4 + r;
#pragma unroll
      for (int db = 0; db < 4; ++db)
        y[(size_t)rowo*NDIM + h*HDIM + db*16 + lrow] = f2b(O[qra][db][r] * inv);
    }
  }
}

// --------- K5: x2/v_next -> out(f32) ; mbuf = rmsnorm(x2) bf16 ---------
__global__ __launch_bounds__(256) void k_fuse_vel(
    const short* __restrict__ xr, const short* __restrict__ aout,
    const float* __restrict__ vel, const float* __restrict__ ascale,
    const float* __restrict__ mu, float* __restrict__ out, short* __restrict__ mbuf) {
  const int row = blockIdx.x;
  const int t = threadIdx.x;
  const int d = t * 4;
  const size_t base = (size_t)row * NDIM + d;
  short4v a4 = *(const short4v*)(xr + base);
  short4v o4 = *(const short4v*)(aout + base);
  float4 vv = *(const float4*)(vel + base);
  float4 as = *(const float4*)(ascale + d);
  float4 mu4 = *(const float4*)(mu + d);
  float xs[4], vns[4];
  const float asl[4] = {as.x, as.y, as.z, as.w};
  const float mul[4] = {mu4.x, mu4.y, mu4.z, mu4.w};
  const float vvl[4] = {vv.x, vv.y, vv.z, vv.w};
#pragma unroll
  for (int i = 0; i < 4; ++i) {
    float x1 = b2f(a4[i]) + asl[i] * b2f(o4[i]);
    float muc = fminf(fmaxf(mul[i], 0.5f), 1.5f);
    float vn = fminf(fmaxf(0.95f*vvl[i] - 0.3f*(x1 - muc), -3.f), 3.f);
    xs[i] = x1 + 0.01f*vn;
    vns[i] = vn;
  }
  float4 x2 = {xs[0], xs[1], xs[2], xs[3]};
  float4 vnq = {vns[0], vns[1], vns[2], vns[3]};
  *(float4*)(out + base) = x2;
  *(float4*)(out + (size_t)NTOK*NDIM + base) = vnq;
  float ss = xs[0]*xs[0] + xs[1]*xs[1] + xs[2]*xs[2] + xs[3]*xs[3];
  ss = wred64(ss);
  __shared__ float wsum[4];
  if ((t & 63) == 0) wsum[t >> 6] = ss;
  __syncthreads();
  float tot = wsum[0] + wsum[1] + wsum[2] + wsum[3];
  float rms = rsqrtf(tot * (1.0f/NDIM) + RMS_EPS);
  short4v m4 = {f2b(xs[0]*rms), f2b(xs[1]*rms), f2b(xs[2]*rms), f2b(xs[3]*rms)};
  *(short4v*)(mbuf + base) = m4;
}

// --------- K6a: token routing (128-row tiles) ---------
__global__ __launch_bounds__(256) void k_route(
    const int* __restrict__ eids, int* __restrict__ rowmap,
    int* __restrict__ tiletab, int* __restrict__ meta) {
  __shared__ int cnt[NEXP];
  __shared__ int ctr[NEXP];
  const int t = threadIdx.x;
  if (t < NEXP) cnt[t] = 0;
  __syncthreads();
  for (int i = t; i < NTOK; i += 256) atomicAdd(&cnt[eids[i]], 1);
  __syncthreads();
  if (t == 0) {
    int off = 0, tile = 0;
    for (int e = 0; e < NEXP; ++e) {
      ctr[e] = off;
      int nt_e = (cnt[e] + 127) >> 7;
      for (int j = 0; j < nt_e; ++j) { tiletab[2*tile] = e; tiletab[2*tile+1] = off + j*128; ++tile; }
      off += cnt[e];
      meta[1 + e] = off;
    }
    meta[0] = tile;
    for (int j = tile; j < MAXTILE; ++j) { tiletab[2*j] = -1; tiletab[2*j+1] = 0; }
  }
  __syncthreads();
  for (int i = t; i < NTOK; i += 256) {
    int e = eids[i];
    int slot = atomicAdd(&ctr[e], 1);
    rowmap[slot] = i;
  }
}

// --------- K6b: h = silu(g)*u from gu rows ---------
__global__ __launch_bounds__(256) void k_silu(
    const short* __restrict__ gu, short* __restrict__ hb) {
  int gid = blockIdx.x * 256 + threadIdx.x;
  int row = gid >> 7, c4 = (gid & 127) * 4;
  short4v g = *(const short4v*)(gu + (size_t)row*1024 + c4);
  short4v u = *(const short4v*)(gu + (size_t)row*1024 + 512 + c4);
  short4v o;
#pragma unroll
  for (int i = 0; i < 4; ++i) {
    float gf = b2f(g[i]), uf = b2f(u[i]);
    o[i] = f2b(gf / (1.0f + __expf(-gf)) * uf);
  }
  *(short4v*)(hb + (size_t)row*512 + c4) = o;
}

extern "C" void kernel_launch(void* const* d_in, const int* in_sizes, int n_in,
                              void* d_out, int out_size, void* d_ws, size_t ws_size,
                              hipStream_t stream) {
  const float* x      = (const float*)d_in[0];
  const float* x0     = (const float*)d_in[1];
  const float* vel    = (const float*)d_in[2];
  const float* rmix   = (const float*)d_in[3];
  const float* ascale = (const float*)d_in[4];
  const float* mscale = (const float*)d_in[5];
  const float* cq_w   = (const float*)d_in[6];
  const float* ck_w   = (const float*)d_in[7];
  const float* cv_w   = (const float*)d_in[8];
  const float* proj_w = (const float*)d_in[9];
  const float* q_gain = (const float*)d_in[10];
  const float* mu     = (const float*)d_in[11];
  const float* gate_up= (const float*)d_in[12];
  const float* down   = (const float*)d_in[13];
  const int*   eids   = (const int*)d_in[14];
  float* out = (float*)d_out;
  char* base = (char*)d_ws;

  const size_t MB = 1024*1024;
  short* wqkv  = (short*)base;
  short* wproj = (short*)(base + 3*MB);
  int*   rowmap  = (int*)(base + 5*MB);
  int*   tiletab = rowmap + NTOK;
  int*   meta    = tiletab + 2*MAXTILE;
  short* wgu_t = (short*)(base + 6*MB);
  short* hbuf  = wgu_t;
  short* xr    = (short*)(base + 22*MB);
  short* gu    = xr;
  short* nbuf  = (short*)(base + 30*MB);
  short* ybuf  = nbuf;
  short* mbuf  = nbuf;
  short* wdn_t = nbuf;
  short* qkv   = (short*)(base + 38*MB);
  short* aout  = qkv;
  short* vbT   = (short*)(base + 50*MB);

  k_w_cast<<<2560, 256, 0, stream>>>(cq_w, ck_w, cv_w, proj_w, wqkv, wproj);
  k_w_transpose<<<dim3(16, 16, 8), 256, 0, stream>>>(gate_up, wgu_t, 1024, 1024);
  k_resid_rms<<<NTOK, 256, 0, stream>>>(x, x0, rmix, xr, nbuf);
  k_gemm_mfma<0><<<dim3(QKVN/128, NTOK/128), 256, 0, stream>>>(
      nbuf, NDIM, wqkv, NDIM, QKVN, qkv, nullptr, QKVN, nullptr, nullptr, nullptr, nullptr);
  k_qk_norm_rope<<<NTOK, 256, 0, stream>>>(qkv, q_gain);
  k_transpose_v<<<NBATCH*NKVH*(NSEQ/64), 256, 0, stream>>>(qkv, vbT);
  k_attn_mfma<<<NBATCH*NHEAD*(NSEQ/128), 256, 0, stream>>>(qkv, vbT, ybuf);
  k_gemm_mfma<0><<<dim3(NDIM/128, NTOK/128), 256, 0, stream>>>(
      ybuf, NDIM, wproj, NDIM, NDIM, aout, nullptr, NDIM, nullptr, nullptr, nullptr, nullptr);
  k_fuse_vel<<<NTOK, 256, 0, stream>>>(xr, aout, vel, ascale, mu, out, mbuf);
  k_route<<<1, 256, 0, stream>>>(eids, rowmap, tiletab, meta);
  k_gemm_mfma<1><<<dim3(1024/128, MAXTILE), 256, 0, stream>>>(
      mbuf, NDIM, wgu_t, NDIM, 1024, gu, nullptr, 1024, rowmap, tiletab, meta, nullptr);
  k_w_transpose<<<dim3(8, 16, 8), 256, 0, stream>>>(down, wdn_t, 512, 1024);
  k_silu<<<(NTOK*512)/(4*256), 256, 0, stream>>>(gu, hbuf);
  k_gemm_mfma<2><<<dim3(NDIM/128, MAXTILE), 256, 0, stream>>>(
      hbuf, NINTER, wdn_t, NINTER, NDIM, nullptr, out, NDIM, rowmap, tiletab, meta, mscale);
}